// Round 7
// baseline (670.721 us; speedup 1.0000x reference)
//
#include <hip/hip_runtime.h>
#include <float.h>

typedef unsigned short ushort_t;
typedef short bf16x8 __attribute__((ext_vector_type(8)));     // 8 bf16 (guide-verified operand type)
typedef _Float16 f16x8 __attribute__((ext_vector_type(8)));   // 8 f16
typedef float f32x4 __attribute__((ext_vector_type(4)));

#define NS 4096
#define ND 64
#define NU 45
#define NUP 48

__device__ __forceinline__ float bf2f(ushort_t u){ return __uint_as_float(((unsigned)u)<<16); }
__device__ __forceinline__ ushort_t f2bf(float f){
  unsigned u = __float_as_uint(f);
  u += 0x7fffu + ((u>>16)&1u);   // RNE
  return (ushort_t)(u>>16);
}
__device__ __forceinline__ ushort_t f2h(float f){ _Float16 h=(_Float16)f; return __builtin_bit_cast(ushort_t, h); }
__device__ __forceinline__ float h2f(ushort_t u){ return (float)__builtin_bit_cast(_Float16, u); }

// ---------------------------------------------------------------------------
// 1) W split+transpose: Wq|Wk|Wv f32 [k][n] -> wh,wl bf16 [1536 n][512 k]
// ---------------------------------------------------------------------------
__global__ __launch_bounds__(256) void k_wsplit(const float* __restrict__ Wq,
                                                const float* __restrict__ Wk,
                                                const float* __restrict__ Wv,
                                                ushort_t* __restrict__ wh,
                                                ushort_t* __restrict__ wl)
{
  int i = blockIdx.x*256 + threadIdx.x;     // < 1536*512
  int c = i >> 9, k = i & 511;
  const float* W = (c < 512) ? Wq : (c < 1024 ? Wk : Wv);
  float v = W[k*512 + (c & 511)];
  ushort_t h = f2bf(v);
  wh[i] = h;
  wl[i] = f2bf(v - bf2f(h));
}

// ---------------------------------------------------------------------------
// 1b) x hi/lo split (once): x f32 -> xh,xl bf16, 4 elems/thread
// ---------------------------------------------------------------------------
__global__ __launch_bounds__(256) void k_xsplit(const float* __restrict__ x,
                                                ushort_t* __restrict__ xh,
                                                ushort_t* __restrict__ xl)
{
  int i = (blockIdx.x*256 + threadIdx.x)*4;
  float4 v = *(const float4*)(x + i);
  ushort4 h, lo;
  h.x = f2bf(v.x); lo.x = f2bf(v.x - bf2f(h.x));
  h.y = f2bf(v.y); lo.y = f2bf(v.y - bf2f(h.y));
  h.z = f2bf(v.z); lo.z = f2bf(v.z - bf2f(h.z));
  h.w = f2bf(v.w); lo.w = f2bf(v.w - bf2f(h.w));
  *(ushort4*)(xh + i) = h;
  *(ushort4*)(xl + i) = lo;
}

// ---------------------------------------------------------------------------
// 2) QKV projection, split-bf16 3-term MFMA (f32-faithful)
//    A staged in LDS; B frags DIRECT from global (L2-resident weights).
//    MODE 0: q (4 col-tiles, inline x convert)  -> qf f32 [bh][n][64]
//    MODE 1: kv (8 col-tiles, staged xh/xl)     -> kf f32 (+kh16 f16 via LDS);
//            v f16 TRANSPOSED via LDS transpose
// ---------------------------------------------------------------------------
template<int MODE>
__global__ __launch_bounds__(256) void k_gemm(
    const float* __restrict__ x,
    const ushort_t* __restrict__ xh, const ushort_t* __restrict__ xl,
    const ushort_t* __restrict__ wh, const ushort_t* __restrict__ wl,
    const float* __restrict__ bq, const float* __restrict__ bk, const float* __restrict__ bv,
    float* __restrict__ qf, float* __restrict__ kf, ushort_t* __restrict__ vfT,
    ushort_t* __restrict__ kh16)
{
  __shared__ __align__(16) ushort_t smem[17408];      // 34.8 KiB: A-stage (20KB) / epilogue transpose (34.8KB)
  ushort_t* Ah = smem;
  ushort_t* Al = smem + 5120;
  const int nbx = (MODE == 0) ? 4 : 8;
  const int p = blockIdx.y * nbx + blockIdx.x;
  const int cx = p & 7;               // XCD slot
  const int local = p >> 3;
  const int by = cx*32 + local/nbx;   // 32 row-panels per XCD chunk
  const int bx = local % nbx;
  const int rowbase = by * 128;
  const int colbase = (MODE == 0 ? 0 : 512) + bx*128;
  const int mat = colbase >> 9;       // 0=q 1=k 2=v
  const int t = threadIdx.x;
  const int l = t & 63;
  const int w = t >> 6;
  const int wm = w >> 1, wn = w & 1;
  f32x4 acc[4][4] = {};
  const int r0 = t >> 2;              // 0..63
  const int c0 = (t & 3) * 8;         // elem offset within 32-wide K slab

  for (int k0 = 0; k0 < 512; k0 += 32) {
    // B frags direct from global (before barrier -> overlaps staging)
    bf16x8 bh8[4], bl8[4];
    #pragma unroll
    for (int n = 0; n < 4; n++) {
      const size_t boff = (size_t)(colbase + wn*64 + n*16 + (l & 15))*512 + k0 + (l >> 4)*8;
      bh8[n] = *(const bf16x8*)(&wh[boff]);
      bl8[n] = *(const bf16x8*)(&wl[boff]);
    }
    __syncthreads();
    #pragma unroll
    for (int half = 0; half < 2; half++) {
      const int r = r0 + half*64;
      if constexpr (MODE == 1) {
        *(uint4*)(&Ah[r*40 + c0]) = *(const uint4*)(&xh[(size_t)(rowbase + r)*512 + k0 + c0]);
        *(uint4*)(&Al[r*40 + c0]) = *(const uint4*)(&xl[(size_t)(rowbase + r)*512 + k0 + c0]);
      } else {
        const float* xp = &x[(size_t)(rowbase + r)*512 + k0 + c0];
        float4 v0 = *(const float4*)xp;
        float4 v1 = *(const float4*)(xp + 4);
        ushort_t hi[8], lo[8];
        float vv[8] = {v0.x,v0.y,v0.z,v0.w,v1.x,v1.y,v1.z,v1.w};
        #pragma unroll
        for (int j = 0; j < 8; j++) {
          hi[j] = f2bf(vv[j]);
          lo[j] = f2bf(vv[j] - bf2f(hi[j]));
        }
        *(uint4*)(&Ah[r*40 + c0]) = *(const uint4*)hi;
        *(uint4*)(&Al[r*40 + c0]) = *(const uint4*)lo;
      }
    }
    __syncthreads();
    bf16x8 ah[4], al[4];
    #pragma unroll
    for (int m = 0; m < 4; m++) {
      const int off = (wm*64 + m*16 + (l & 15))*40 + (l >> 4)*8;
      ah[m] = *(const bf16x8*)(&Ah[off]);
      al[m] = *(const bf16x8*)(&Al[off]);
    }
    #pragma unroll
    for (int m = 0; m < 4; m++)
      #pragma unroll
      for (int n = 0; n < 4; n++) {
        acc[m][n] = __builtin_amdgcn_mfma_f32_16x16x32_bf16(ah[m], bh8[n], acc[m][n], 0, 0, 0);
        acc[m][n] = __builtin_amdgcn_mfma_f32_16x16x32_bf16(ah[m], bl8[n], acc[m][n], 0, 0, 0);
        acc[m][n] = __builtin_amdgcn_mfma_f32_16x16x32_bf16(al[m], bh8[n], acc[m][n], 0, 0, 0);
      }
  }

  if (MODE == 0 || mat == 1) {
    // direct f32 writes: each (m,n,j) slice covers aligned 64B row segments
    const float* bias_p = (MODE == 0) ? bq : bk;
    float* dst = (MODE == 0) ? qf : kf;
    #pragma unroll
    for (int n = 0; n < 4; n++) {
      const int wi = (colbase & 511) + wn*64 + n*16 + (l & 15);
      const int hh = wi >> 6, d = wi & 63;
      const float bias = bias_p[wi];
      #pragma unroll
      for (int m = 0; m < 4; m++) {
        const int rb = rowbase + wm*64 + m*16 + ((l >> 4) << 2);
        const int b  = rb >> 12, nr = rb & 4095;
        #pragma unroll
        for (int j = 0; j < 4; j++)
          dst[((size_t)(b*8 + hh)*NS + nr + j)*ND + d] = acc[m][n][j] + bias;
      }
    }
    if (MODE == 1 && kh16) {
      // kh16 via LDS: stage [128 row][136 col] f16, then 128B coalesced rows
      __syncthreads();
      #pragma unroll
      for (int n = 0; n < 4; n++) {
        const int c_l = wn*64 + n*16 + (l & 15);
        const float bias = bk[(colbase & 511) + c_l];
        #pragma unroll
        for (int m = 0; m < 4; m++) {
          const int rb_l = wm*64 + m*16 + ((l >> 4) << 2);
          #pragma unroll
          for (int j = 0; j < 4; j++)
            smem[(rb_l + j)*136 + c_l] = f2h(acc[m][n][j] + bias);
        }
      }
      __syncthreads();
      const int r2 = t >> 1, half = t & 1;
      const int hh2 = ((colbase & 511) >> 6) + half;
      const int b2 = rowbase >> 12;
      const int nr2 = rowbase & 4095;
      ushort_t* op = &kh16[((size_t)(b2*8 + hh2)*NS + nr2 + r2)*ND];
      const ushort_t* ip = &smem[r2*136 + half*64];
      #pragma unroll
      for (int cch = 0; cch < 8; cch++)
        *(uint4*)(op + cch*8) = *(const uint4*)(ip + cch*8);
    }
  } else {
    // v: LDS transpose then coalesced 128B vfT row-segment writes
    __syncthreads();                  // all MFMA LDS reads done
    #pragma unroll
    for (int n = 0; n < 4; n++) {
      const int wi_l = wn*64 + n*16 + (l & 15);
      const float bias = bv[(colbase & 511) + wi_l];
      #pragma unroll
      for (int m = 0; m < 4; m++) {
        const int nr_l = wm*64 + m*16 + ((l >> 4) << 2);
        ushort4 pk;
        pk.x = f2h(acc[m][n][0] + bias);
        pk.y = f2h(acc[m][n][1] + bias);
        pk.z = f2h(acc[m][n][2] + bias);
        pk.w = f2h(acc[m][n][3] + bias);
        *(ushort4*)(&smem[wi_l*136 + nr_l]) = pk;   // [128 wi][136] f16, padded
      }
    }
    __syncthreads();
    const int wi2 = t >> 1, half = t & 1;
    const int cim = (colbase & 511) + wi2;
    const int hh2 = cim >> 6, d2 = cim & 63;
    const int b2 = rowbase >> 12;
    const int nr2 = (rowbase & 4095) + half*64;
    ushort_t* op = &vfT[((size_t)(b2*8 + hh2)*ND + d2)*NS + nr2];
    const ushort_t* ip = &smem[wi2*136 + half*64];
    #pragma unroll
    for (int cch = 0; cch < 8; cch++)
      *(uint4*)(op + cch*8) = *(const uint4*)(ip + cch*8);
  }
}

// ---------------------------------------------------------------------------
// 3a) APPROX M from f16 k: wave per query, 8 lanes per sample-row
// ---------------------------------------------------------------------------
__global__ __launch_bounds__(256) void k_m_approx(const float* __restrict__ qf,
                                                  const ushort_t* __restrict__ kh16,
                                                  const int* __restrict__ idxs,
                                                  float* __restrict__ Mv)
{
  __shared__ float qs[4][64];
  __shared__ int   sidx[4][48];
  const int orig = blockIdx.y * 1024 + blockIdx.x;
  const int lin  = (orig & 7) * 8192 + (orig >> 3);   // bijective XCD swizzle
  const int bh   = lin >> 10;
  const int lc   = lin & 1023;
  const int t = threadIdx.x;
  const int wv = t >> 6, lane = t & 63;
  const int l = lc*4 + wv;
  qs[wv][lane] = qf[((size_t)bh*NS + l)*ND + lane];
  for (int e = t; e < 4*NU; e += 256)
    sidx[e/NU][e%NU] = idxs[(size_t)(lc*4 + e/NU)*NU + e%NU];
  __syncthreads();
  const int g  = lane >> 3;       // sample group 0..7
  const int dq = lane & 7;        // 8 f16 at dq*8
  const float* qp = &qs[wv][dq*8];
  float mx = -FLT_MAX, sm = 0.f;
  #pragma unroll
  for (int p = 0; p < 6; p++) {
    const int s = p*8 + g;
    const bool val = (s < NU);
    const int id = sidx[wv][val ? s : NU-1];
    uint4 ku = *(const uint4*)(&kh16[((size_t)bh*NS + id)*ND + dq*8]);
    f16x8 k8 = __builtin_bit_cast(f16x8, ku);
    float p_dot = qp[0]*(float)k8[0] + qp[1]*(float)k8[1] + qp[2]*(float)k8[2] + qp[3]*(float)k8[3]
                + qp[4]*(float)k8[4] + qp[5]*(float)k8[5] + qp[6]*(float)k8[6] + qp[7]*(float)k8[7];
    p_dot += __shfl_xor(p_dot, 1, 64);
    p_dot += __shfl_xor(p_dot, 2, 64);
    p_dot += __shfl_xor(p_dot, 4, 64);
    if (val) { mx = fmaxf(mx, p_dot); sm += p_dot; }
  }
  #pragma unroll
  for (int o = 8; o < 64; o <<= 1) {
    mx = fmaxf(mx, __shfl_xor(mx, o, 64));
    sm += __shfl_xor(sm, o, 64);
  }
  if (lane == 0) Mv[bh*NS + l] = mx - sm * (1.0f/(float)NS);
}

// 3b) exact M (fallback path)
__global__ __launch_bounds__(256) void k_m_exact_full(const float* __restrict__ qf,
                                                      const float* __restrict__ kf,
                                                      const int* __restrict__ idxs,
                                                      float* __restrict__ Mv)
{
  const int bh = blockIdx.y;
  const int l  = blockIdx.x*4 + (threadIdx.x >> 6);
  const int lane = threadIdx.x & 63;
  const int g  = lane >> 2;
  const int dq = lane & 3;
  const float* qrow = qf + ((size_t)bh*NS + l)*ND + dq*16;
  const float4 q0 = *(const float4*)(qrow + 0);
  const float4 q1 = *(const float4*)(qrow + 4);
  const float4 q2 = *(const float4*)(qrow + 8);
  const float4 q3 = *(const float4*)(qrow + 12);
  const float* kbase = kf + (size_t)bh*NS*ND;
  const int* ib = idxs + (size_t)l*NU;
  float mx = -FLT_MAX, sm = 0.f;
  #pragma unroll
  for (int p3 = 0; p3 < 3; p3++) {
    const int s = p3*16 + g;
    const int id = ib[s < NU ? s : NU-1];
    const float* kr = kbase + (size_t)id*ND + dq*16;
    const float4 k0 = *(const float4*)(kr + 0);
    const float4 k1 = *(const float4*)(kr + 4);
    const float4 k2 = *(const float4*)(kr + 8);
    const float4 k3 = *(const float4*)(kr + 12);
    float p = q0.x*k0.x + q0.y*k0.y + q0.z*k0.z + q0.w*k0.w
            + q1.x*k1.x + q1.y*k1.y + q1.z*k1.z + q1.w*k1.w
            + q2.x*k2.x + q2.y*k2.y + q2.z*k2.z + q2.w*k2.w
            + q3.x*k3.x + q3.y*k3.y + q3.z*k3.z + q3.w*k3.w;
    p += __shfl_xor(p, 1, 64);
    p += __shfl_xor(p, 2, 64);
    if (s < NU) { mx = fmaxf(mx, p); sm += p; }
  }
  #pragma unroll
  for (int o = 4; o < 64; o <<= 1) {
    mx = fmaxf(mx, __shfl_xor(mx, o, 64));
    sm += __shfl_xor(sm, o, 64);
  }
  if (lane == 0) Mv[bh*NS + l] = mx - sm * (1.0f/(float)NS);
}

// ---------------------------------------------------------------------------
// 4) top-NSEL per (b,h): register-cached iterative argmax
// ---------------------------------------------------------------------------
template<int NSEL, int OST>
__global__ __launch_bounds__(256) void k_topk(const float* __restrict__ Mv, int* __restrict__ dst)
{
  __shared__ float wvs[4];
  __shared__ int   wis[4];
  const int bh = blockIdx.x, t = threadIdx.x;
  const int wv = t >> 6, lane = t & 63;
  float v[16];
  #pragma unroll
  for (int j = 0; j < 16; j++) v[j] = Mv[bh*NS + j*256 + t];
  unsigned removed = 0;
  float tmax = -FLT_MAX; int tidx = 0x7fffffff;
  #pragma unroll
  for (int j = 0; j < 16; j++) {
    if (v[j] > tmax) { tmax = v[j]; tidx = j*256 + t; }
  }
  for (int it = 0; it < NSEL; it++) {
    float mv = tmax; int mi = tidx;
    #pragma unroll
    for (int o = 1; o < 64; o <<= 1) {
      float vo = __shfl_xor(mv, o, 64); int io = __shfl_xor(mi, o, 64);
      if (vo > mv || (vo == mv && io < mi)) { mv = vo; mi = io; }
    }
    if (lane == 0) { wvs[wv] = mv; wis[wv] = mi; }
    __syncthreads();
    float gv = wvs[0]; int gi = wis[0];
    #pragma unroll
    for (int k2 = 1; k2 < 4; k2++) {
      float vo = wvs[k2]; int io = wis[k2];
      if (vo > gv || (vo == gv && io < gi)) { gv = vo; gi = io; }
    }
    if (t == 0) dst[bh*OST + it] = gi;
    if ((gi & 255) == t) {       // owner invalidates and rescans its 16
      removed |= 1u << (gi >> 8);
      tmax = -FLT_MAX; tidx = 0x7fffffff;
      #pragma unroll
      for (int j = 0; j < 16; j++) {
        bool ok = ((removed >> j) & 1u) == 0u;
        if (ok && (v[j] > tmax || (v[j] == tmax && (j*256+t) < tidx))) { tmax = v[j]; tidx = j*256 + t; }
      }
    }
    __syncthreads();
  }
}

// ---------------------------------------------------------------------------
// 4b) exact M for the 64 candidates: 16 lanes per candidate
// ---------------------------------------------------------------------------
__global__ __launch_bounds__(256) void k_mexact(const float* __restrict__ qf,
                                                const float* __restrict__ kf,
                                                const int* __restrict__ idxs,
                                                const int* __restrict__ Cand,
                                                float* __restrict__ Mex)
{
  const int bh = blockIdx.y, qtr = blockIdx.x, t = threadIdx.x;
  const int c = qtr*16 + (t >> 4);
  const int dl = t & 15;                    // 4 floats at dl*4
  const int l = Cand[bh*64 + c];
  const float4 q4 = *(const float4*)(&qf[((size_t)bh*NS + l)*ND + dl*4]);
  const float* kbase = kf + (size_t)bh*NS*ND;
  const int* ib = idxs + (size_t)l*NU;
  float mx = -FLT_MAX, sm = 0.f;
  for (int s = 0; s < NU; s++) {
    const int id = ib[s];
    const float4 k4 = *(const float4*)(&kbase[(size_t)id*ND + dl*4]);
    float p = q4.x*k4.x + q4.y*k4.y + q4.z*k4.z + q4.w*k4.w;
    p += __shfl_xor(p, 1, 64);
    p += __shfl_xor(p, 2, 64);
    p += __shfl_xor(p, 4, 64);
    p += __shfl_xor(p, 8, 64);
    mx = fmaxf(mx, p);
    sm += p;
  }
  if (dl == 0) Mex[bh*64 + c] = mx - sm * (1.0f/(float)NS);
}

// 4c) exact top-45 of the 64 candidates (value desc, index asc)
__global__ void k_sel45(const float* __restrict__ Mex, const int* __restrict__ Cand,
                        int* __restrict__ Mtop)
{
  const int bh = blockIdx.x, lane = threadIdx.x;   // 64 threads
  float val = Mex[bh*64 + lane];
  const int n = Cand[bh*64 + lane];
  for (int it = 0; it < NU; it++) {
    float wv = val; int wn = n;
    #pragma unroll
    for (int o = 1; o < 64; o <<= 1) {
      float vo = __shfl_xor(wv, o, 64); int io = __shfl_xor(wn, o, 64);
      if (vo > wv || (vo == wv && io < wn)) { wv = vo; wn = io; }
    }
    if (lane == 0) Mtop[bh*NUP + it] = wn;
    if (n == wn) val = -FLT_MAX;
  }
}

// ---------------------------------------------------------------------------
// 5) Q_reduce gather -> bf16 [bh][48][64] (rows 45..47 zero)
// ---------------------------------------------------------------------------
__global__ __launch_bounds__(256) void k_qreduce(const float* __restrict__ qf,
                                                 const int* __restrict__ Mtop,
                                                 ushort_t* __restrict__ Qr)
{
  const int bh = blockIdx.x, t = threadIdx.x;
  for (int e = t; e < NUP*ND; e += 256) {
    const int u = e >> 6, d = e & 63;
    float v = 0.f;
    if (u < NU) { const int r = Mtop[bh*NUP + u]; v = qf[((size_t)bh*NS + r)*ND + d]; }
    Qr[bh*NUP*ND + e] = f2bf(v);
  }
}

// ---------------------------------------------------------------------------
// 6) scores[bh][48][4096] = bf16( 0.125 * Qr @ k^T )
// ---------------------------------------------------------------------------
__global__ __launch_bounds__(256) void k_scores(const ushort_t* __restrict__ Qr,
                                                const float* __restrict__ kf,
                                                ushort_t* __restrict__ scores)
{
  __shared__ __align__(16) ushort_t Ql[NUP*80];
  const int bh = blockIdx.y;
  const int n0 = blockIdx.x * 256;
  const int t = threadIdx.x, w = t >> 6, l = t & 63;
  for (int chunk = t; chunk < NUP*8; chunk += 256) {
    const int r = chunk >> 3, cp = chunk & 7;
    *(uint4*)(&Ql[r*80 + cp*8]) = *(const uint4*)(&Qr[((size_t)bh*NUP + r)*ND + cp*8]);
  }
  __syncthreads();
  f32x4 acc[3][4] = {};
  const float* kbb = kf + (size_t)bh*NS*ND;
  const int nw = n0 + w*64;
  #pragma unroll
  for (int ks = 0; ks < 2; ks++) {
    bf16x8 a[3], b8[4];
    #pragma unroll
    for (int m = 0; m < 3; m++)
      a[m] = *(const bf16x8*)(&Ql[(m*16 + (l & 15))*80 + (l >> 4)*8 + ks*32]);
    #pragma unroll
    for (int n = 0; n < 4; n++) {
      const float* kr = &kbb[(size_t)(nw + n*16 + (l & 15))*ND + (l >> 4)*8 + ks*32];
      float4 u0 = *(const float4*)kr;
      float4 u1 = *(const float4*)(kr + 4);
      ushort_t tmp[8] = {f2bf(u0.x),f2bf(u0.y),f2bf(u0.z),f2bf(u0.w),
                         f2bf(u1.x),f2bf(u1.y),f2bf(u1.z),f2bf(u1.w)};
      b8[n] = *(const bf16x8*)tmp;
    }
    #pragma unroll
    for (int m = 0; m < 3; m++)
      #pragma unroll
      for (int n = 0; n < 4; n++)
        acc[m][n] = __builtin_amdgcn_mfma_f32_16x16x32_bf16(a[m], b8[n], acc[m][n], 0, 0, 0);
  }
  #pragma unroll
  for (int m = 0; m < 3; m++)
    #pragma unroll
    for (int n = 0; n < 4; n++)
      #pragma unroll
      for (int j = 0; j < 4; j++) {
        const int row = m*16 + (l >> 4)*4 + j;
        const int col = nw + n*16 + (l & 15);
        scores[((size_t)bh*NUP + row)*NS + col] = f2bf(acc[m][n][j] * 0.125f);
      }
}

// ---------------------------------------------------------------------------
// 7) softmax: bf16 scores row -> f16 attn row, in place (u<45 only)
// ---------------------------------------------------------------------------
__global__ __launch_bounds__(256) void k_softmax(ushort_t* __restrict__ scores)
{
  __shared__ float srow[NS];
  __shared__ float red[256];
  const int bh = blockIdx.y, u = blockIdx.x, t = threadIdx.x;
  ushort_t* row = scores + ((size_t)bh*NUP + u)*NS;
  float mx = -FLT_MAX;
  for (int j = t; j < NS; j += 256) { float v = bf2f(row[j]); srow[j] = v; mx = fmaxf(mx, v); }
  red[t] = mx; __syncthreads();
  for (int s = 128; s > 0; s >>= 1) { if (t < s) red[t] = fmaxf(red[t], red[t+s]); __syncthreads(); }
  mx = red[0]; __syncthreads();
  float sm = 0.f;
  for (int j = t; j < NS; j += 256) { const float e = __expf(srow[j] - mx); srow[j] = e; sm += e; }
  red[t] = sm; __syncthreads();
  for (int s = 128; s > 0; s >>= 1) { if (t < s) red[t] += red[t+s]; __syncthreads(); }
  const float inv = 1.0f / red[0];
  for (int j = t; j < NS; j += 256) row[j] = f2h(srow[j] * inv);
}

// ---------------------------------------------------------------------------
// 8) v mean from vfT (one block per (bh,d), deterministic)
// ---------------------------------------------------------------------------
__global__ __launch_bounds__(256) void k_vmean(const ushort_t* __restrict__ vfT, float* __restrict__ vmean)
{
  __shared__ float red[256];
  const int d = blockIdx.x, bh = blockIdx.y, t = threadIdx.x;
  const ushort_t* vr = vfT + ((size_t)bh*ND + d)*NS;
  float s = 0.f;
  for (int n = t; n < NS; n += 256) s += h2f(vr[n]);
  red[t] = s; __syncthreads();
  for (int st = 128; st > 0; st >>= 1) { if (t < st) red[t] += red[t+st]; __syncthreads(); }
  if (t == 0) vmean[bh*ND + d] = red[0] * (1.0f/(float)NS);
}

// ---------------------------------------------------------------------------
// 9) PV partials via f16 MFMA: pout[bh][ch][48][64] over 8 NS-chunks of 512
// ---------------------------------------------------------------------------
__global__ __launch_bounds__(256) void k_outu(const ushort_t* __restrict__ attn,
                                              const ushort_t* __restrict__ vfT,
                                              float* __restrict__ pout)
{
  const int bh = blockIdx.y, ch = blockIdx.x;
  const int t = threadIdx.x, w = t >> 6, l = t & 63;
  if (w >= 3) return;               // 3 row-tiles of 16 (48 rows); no syncs below
  const ushort_t* ab = attn + (size_t)bh*NUP*NS;
  const ushort_t* vb = vfT + (size_t)bh*ND*NS;
  f32x4 acc[4] = {};
  const int arow = w*16 + (l & 15);
  const int koff = (l >> 4)*8;
  const int kbeg = ch*512;
  for (int kc = kbeg; kc < kbeg + 512; kc += 32) {
    uint4 au = *(const uint4*)(&ab[(size_t)arow*NS + kc + koff]);
    f16x8 a = __builtin_bit_cast(f16x8, au);
    #pragma unroll
    for (int nt = 0; nt < 4; nt++) {
      uint4 bu = *(const uint4*)(&vb[(size_t)(nt*16 + (l & 15))*NS + kc + koff]);
      f16x8 b = __builtin_bit_cast(f16x8, bu);
      acc[nt] = __builtin_amdgcn_mfma_f32_16x16x32_f16(a, b, acc[nt], 0, 0, 0);
    }
  }
  #pragma unroll
  for (int nt = 0; nt < 4; nt++)
    #pragma unroll
    for (int j = 0; j < 4; j++) {
      const int u = w*16 + (l >> 4)*4 + j;
      const int d = nt*16 + (l & 15);
      pout[(((size_t)bh*8 + ch)*NUP + u)*ND + d] = acc[nt][j];
    }
}

__global__ __launch_bounds__(256) void k_delta_fin(const float* __restrict__ pout,
                                                   const float* __restrict__ vmean,
                                                   float* __restrict__ delta)
{
  const int bh = blockIdx.x, t = threadIdx.x;
  for (int e = t; e < NUP*ND; e += 256) {
    const int u = e >> 6, d = e & 63;
    float s = 0.f;
    #pragma unroll
    for (int ch = 0; ch < 8; ch++) s += pout[(((size_t)bh*8 + ch)*NUP + u)*ND + d];
    delta[((size_t)bh*NUP + u)*ND + d] = s - vmean[bh*ND + d];
  }
}

// ---------------------------------------------------------------------------
// 10) row-id map
// ---------------------------------------------------------------------------
__global__ __launch_bounds__(256) void k_uidx_init(int* __restrict__ uidx)
{
  uidx[blockIdx.x*256 + threadIdx.x] = -1;
}

__global__ void k_scatter(const int* __restrict__ Mtop, int* __restrict__ uidx)
{
  const int bh = blockIdx.x, t = threadIdx.x;  // 64 threads
  if (t < NU) {
    const int n = Mtop[bh*NUP + t];
    const int b = bh >> 3, h = bh & 7;
    const int nprime = h*512 + (n >> 3);       // reference's reshape-without-transpose
    uidx[((size_t)b*NS + nprime)*8 + (n & 7)] = bh*NUP + t;
  }
}

// ---------------------------------------------------------------------------
// 11) corrections: corr[bh*48+u][512] = delta @ Wp[j*64:(j+1)*64, :]   (f32)
// ---------------------------------------------------------------------------
__global__ __launch_bounds__(256) void k_corr(const float* __restrict__ delta,
                                              const float* __restrict__ Wp,
                                              const int* __restrict__ Mtop,
                                              float* __restrict__ corr)
{
  __shared__ float dl[64];
  const int bh = blockIdx.y, u = blockIdx.x, t = threadIdx.x;
  const int n = Mtop[bh*NUP + u];
  const int j = n & 7;
  if (t < 64) dl[t] = delta[((size_t)bh*NUP + u)*ND + t];
  __syncthreads();
  for (int c = t; c < 512; c += 256) {
    float s = 0.f;
    #pragma unroll 8
    for (int d2 = 0; d2 < 64; d2++) s += dl[d2] * Wp[(size_t)(j*64 + d2)*512 + c];
    corr[((size_t)bh*NUP + u)*512 + c] = s;
  }
}

// ---------------------------------------------------------------------------
// 12) base rows: basep[bh][512] = (vmean tiled 8x) @ Wp + bp  (f32)
// ---------------------------------------------------------------------------
__global__ __launch_bounds__(256) void k_base(const float* __restrict__ vmean,
                                              const float* __restrict__ Wp,
                                              const float* __restrict__ bp,
                                              float* __restrict__ basep)
{
  __shared__ float vm[64];
  const int bh = blockIdx.x, t = threadIdx.x;
  if (t < 64) vm[t] = vmean[bh*ND + t];
  __syncthreads();
  for (int c = t; c < 512; c += 256) {
    float s = bp[c];
    for (int k = 0; k < 512; k++) s += vm[k & 63] * Wp[(size_t)k*512 + c];
    basep[bh*512 + c] = s;
  }
}

// ---------------------------------------------------------------------------
// 13) assemble output rows (f32)
// ---------------------------------------------------------------------------
__global__ __launch_bounds__(256) void k_assemble(const float* __restrict__ basep,
                                                  const float* __restrict__ corr,
                                                  const int* __restrict__ uidx,
                                                  float* __restrict__ out)
{
  const int b = blockIdx.y, nprime = blockIdx.x, t = threadIdx.x;
  const int h = nprime >> 9;
  const int* ui = uidx + ((size_t)b*NS + nprime)*8;
  float v0 = basep[(b*8 + h)*512 + t];
  float v1 = basep[(b*8 + h)*512 + 256 + t];
  #pragma unroll
  for (int j = 0; j < 8; j++) {
    const int id = ui[j];
    if (id >= 0) { v0 += corr[(size_t)id*512 + t]; v1 += corr[(size_t)id*512 + 256 + t]; }
  }
  const size_t o = ((size_t)b*NS + nprime)*512;
  out[o + t]       = v0;
  out[o + 256 + t] = v1;
}

// ---------------------------------------------------------------------------
extern "C" void kernel_launch(void* const* d_in, const int* in_sizes, int n_in,
                              void* d_out, int out_size, void* d_ws, size_t ws_size,
                              hipStream_t stream)
{
  (void)in_sizes; (void)n_in; (void)out_size;
  const float* x  = (const float*)d_in[0];
  const float* Wq = (const float*)d_in[1];
  const float* bq = (const float*)d_in[2];
  const float* Wk = (const float*)d_in[3];
  const float* bk = (const float*)d_in[4];
  const float* Wv = (const float*)d_in[5];
  const float* bv = (const float*)d_in[6];
  const float* Wp = (const float*)d_in[7];
  const float* bp = (const float*)d_in[8];
  const int* idxs = (const int*)d_in[9];
  float* out      = (float*)d_out;

  // base workspace carve-up; stage-2 buffers alias dead qf region
  char* w = (char*)d_ws;
  float*    qf    = (float*)(w);                    // 67,108,864  [64][4096][64] f32
  float*    kf    = (float*)(w + 67108864);         // 67,108,864
  ushort_t* vfT   = (ushort_t*)(w + 134217728);     // 33,554,432  [64][64][4096] f16
  ushort_t* wh    = (ushort_t*)(w + 167772160);     //  1,572,864
  ushort_t* wl    = (ushort_t*)(w + 169345024);     //  1,572,864
  float*    Mv    = (float*)(w + 170917888);        //  1,048,576
  int*      Mtop  = (int*)(w + 171966464);          //     12,288
  ushort_t* Qr    = (ushort_t*)(w + 171978752);     //    393,216
  float*    vmean = (float*)(w + 172371968);        //     16,384  -> 172,388,352
  // xh/xl alias the qf region (live only until the q-gemm runs):
  ushort_t* xh = (ushort_t*)(w);                    // 33,554,432
  ushort_t* xl = (ushort_t*)(w + 33554432);         // 33,554,432
  // aliases inside qf (valid only after k_qreduce):
  ushort_t* scores = (ushort_t*)(w);                // 25,165,824  [64][48][4096] bf16->f16
  float*    delta  = (float*)(w + 25165824);        //    786,432
  float*    corr   = (float*)(w + 25952256);        //  6,291,456
  int*      uidx   = (int*)(w + 32243712);          //  1,048,576
  float*    basep  = (float*)(w + 33292288);        //    131,072
  float*    pout   = (float*)(w + 33423360);        //  6,291,456  [64][8][48][64]
  // approx-M extension:
  ushort_t* kh16 = (ushort_t*)(w + 172388352);      // 33,554,432  [64][4096][64] f16
  int*      Cand = (int*)(w + 205942784);           //     16,384  [64][64]
  float*    Mex  = (float*)(w + 205959168);         //     16,384  -> end 205,975,552
  const bool approx_ok = (ws_size >= (size_t)205975552);
  ushort_t* kh16_arg = approx_ok ? kh16 : (ushort_t*)nullptr;

  k_wsplit   <<<3072, 256, 0, stream>>>(Wq, Wk, Wv, wh, wl);
  k_xsplit   <<<16384, 256, 0, stream>>>(x, xh, xl);
  k_gemm<1>  <<<dim3(8, 256), 256, 0, stream>>>(x, xh, xl, wh, wl, bq, bk, bv, qf, kf, vfT, kh16_arg);
  k_gemm<0>  <<<dim3(4, 256), 256, 0, stream>>>(x, nullptr, nullptr, wh, wl, bq, bk, bv, qf, kf, vfT, nullptr);
  if (approx_ok) {
    k_m_approx <<<dim3(1024, 64), 256, 0, stream>>>(qf, kh16, idxs, Mv);
    k_vmean    <<<dim3(64, 64), 256, 0, stream>>>(vfT, vmean);
    k_topk<64,64> <<<64, 256, 0, stream>>>(Mv, Cand);
    k_mexact   <<<dim3(4, 64), 256, 0, stream>>>(qf, kf, idxs, Cand, Mex);
    k_sel45    <<<64, 64, 0, stream>>>(Mex, Cand, Mtop);
  } else {
    k_m_exact_full <<<dim3(1024, 64), 256, 0, stream>>>(qf, kf, idxs, Mv);
    k_vmean    <<<dim3(64, 64), 256, 0, stream>>>(vfT, vmean);
    k_topk<NU,NUP> <<<64, 256, 0, stream>>>(Mv, Mtop);
  }
  k_qreduce  <<<64, 256, 0, stream>>>(qf, Mtop, Qr);
  // qf dead from here; aliases live
  k_scores   <<<dim3(16, 64), 256, 0, stream>>>(Qr, kf, scores);
  k_softmax  <<<dim3(45, 64), 256, 0, stream>>>(scores);
  k_outu     <<<dim3(8, 64), 256, 0, stream>>>(scores, vfT, pout);
  k_delta_fin<<<64, 256, 0, stream>>>(pout, vmean, delta);
  k_uidx_init<<<1024, 256, 0, stream>>>(uidx);
  k_scatter  <<<64, 64, 0, stream>>>(Mtop, uidx);
  k_corr     <<<dim3(45, 64), 256, 0, stream>>>(delta, Wp, Mtop, corr);
  k_base     <<<64, 256, 0, stream>>>(vmean, Wp, bp, basep);
  k_assemble <<<dim3(4096, 8), 256, 0, stream>>>(basep, corr, uidx, out);
}

// Round 8
// 602.589 us; speedup vs baseline: 1.1131x; 1.1131x over previous
//
#include <hip/hip_runtime.h>
#include <float.h>

typedef unsigned short ushort_t;
typedef short bf16x8 __attribute__((ext_vector_type(8)));     // 8 bf16 (guide-verified operand type)
typedef _Float16 f16x8 __attribute__((ext_vector_type(8)));   // 8 f16
typedef float f32x4 __attribute__((ext_vector_type(4)));

#define NS 4096
#define ND 64
#define NU 45
#define NUP 48

__device__ __forceinline__ float bf2f(ushort_t u){ return __uint_as_float(((unsigned)u)<<16); }
__device__ __forceinline__ ushort_t f2bf(float f){
  unsigned u = __float_as_uint(f);
  u += 0x7fffu + ((u>>16)&1u);   // RNE
  return (ushort_t)(u>>16);
}
__device__ __forceinline__ ushort_t f2h(float f){ _Float16 h=(_Float16)f; return __builtin_bit_cast(ushort_t, h); }
__device__ __forceinline__ float h2f(ushort_t u){ return (float)__builtin_bit_cast(_Float16, u); }

// ---------------------------------------------------------------------------
// 1) W split+transpose: Wq|Wk|Wv f32 [k][n] -> wh,wl bf16 [1536 n][512 k]
// ---------------------------------------------------------------------------
__global__ __launch_bounds__(256) void k_wsplit(const float* __restrict__ Wq,
                                                const float* __restrict__ Wk,
                                                const float* __restrict__ Wv,
                                                ushort_t* __restrict__ wh,
                                                ushort_t* __restrict__ wl)
{
  int i = blockIdx.x*256 + threadIdx.x;     // < 1536*512
  int c = i >> 9, k = i & 511;
  const float* W = (c < 512) ? Wq : (c < 1024 ? Wk : Wv);
  float v = W[k*512 + (c & 511)];
  ushort_t h = f2bf(v);
  wh[i] = h;
  wl[i] = f2bf(v - bf2f(h));
}

// ---------------------------------------------------------------------------
// 1b) x hi/lo split (once): x f32 -> xh,xl bf16, 4 elems/thread
// ---------------------------------------------------------------------------
__global__ __launch_bounds__(256) void k_xsplit(const float* __restrict__ x,
                                                ushort_t* __restrict__ xh,
                                                ushort_t* __restrict__ xl)
{
  int i = (blockIdx.x*256 + threadIdx.x)*4;
  float4 v = *(const float4*)(x + i);
  ushort4 h, lo;
  h.x = f2bf(v.x); lo.x = f2bf(v.x - bf2f(h.x));
  h.y = f2bf(v.y); lo.y = f2bf(v.y - bf2f(h.y));
  h.z = f2bf(v.z); lo.z = f2bf(v.z - bf2f(h.z));
  h.w = f2bf(v.w); lo.w = f2bf(v.w - bf2f(h.w));
  *(ushort4*)(xh + i) = h;
  *(ushort4*)(xl + i) = lo;
}

// ---------------------------------------------------------------------------
// 2) QKV projection, split-bf16 3-term MFMA (f32-faithful)
//    A and B both staged in LDS (round-6 proven structure).
//    MODE 0: q (4 col-tiles, inline x convert)  -> qf f32 [bh][n][64]
//    MODE 1: kv (8 col-tiles, staged xh/xl)     -> kf f32 (+kb16 bf16 via LDS);
//            v f16 TRANSPOSED via LDS transpose
// ---------------------------------------------------------------------------
template<int MODE>
__global__ __launch_bounds__(256) void k_gemm(
    const float* __restrict__ x,
    const ushort_t* __restrict__ xh, const ushort_t* __restrict__ xl,
    const ushort_t* __restrict__ wh, const ushort_t* __restrict__ wl,
    const float* __restrict__ bq, const float* __restrict__ bk, const float* __restrict__ bv,
    float* __restrict__ qf, float* __restrict__ kf, ushort_t* __restrict__ vfT,
    ushort_t* __restrict__ kb16)
{
  __shared__ __align__(16) ushort_t smem[20480];      // 40 KiB: 4 stage bufs / epilogue transpose (34.8KB)
  ushort_t* Ah = smem;
  ushort_t* Al = smem + 5120;
  ushort_t* Bh = smem + 10240;
  ushort_t* Bl = smem + 15360;
  const int nbx = (MODE == 0) ? 4 : 8;
  const int p = blockIdx.y * nbx + blockIdx.x;
  const int cx = p & 7;               // XCD slot
  const int local = p >> 3;
  const int by = cx*32 + local/nbx;   // 32 row-panels per XCD chunk
  const int bx = local % nbx;
  const int rowbase = by * 128;
  const int colbase = (MODE == 0 ? 0 : 512) + bx*128;
  const int mat = colbase >> 9;       // 0=q 1=k 2=v
  const int t = threadIdx.x;
  const int l = t & 63;
  const int w = t >> 6;
  const int wm = w >> 1, wn = w & 1;
  f32x4 acc[4][4] = {};
  const int r0 = t >> 2;              // 0..63
  const int c0 = (t & 3) * 8;         // elem offset within 32-wide K slab

  for (int k0 = 0; k0 < 512; k0 += 32) {
    __syncthreads();
    #pragma unroll
    for (int half = 0; half < 2; half++) {
      const int r = r0 + half*64;
      if constexpr (MODE == 1) {
        *(uint4*)(&Ah[r*40 + c0]) = *(const uint4*)(&xh[(size_t)(rowbase + r)*512 + k0 + c0]);
        *(uint4*)(&Al[r*40 + c0]) = *(const uint4*)(&xl[(size_t)(rowbase + r)*512 + k0 + c0]);
      } else {
        const float* xp = &x[(size_t)(rowbase + r)*512 + k0 + c0];
        float4 v0 = *(const float4*)xp;
        float4 v1 = *(const float4*)(xp + 4);
        ushort_t hi[8], lo[8];
        float vv[8] = {v0.x,v0.y,v0.z,v0.w,v1.x,v1.y,v1.z,v1.w};
        #pragma unroll
        for (int j = 0; j < 8; j++) {
          hi[j] = f2bf(vv[j]);
          lo[j] = f2bf(vv[j] - bf2f(hi[j]));
        }
        *(uint4*)(&Ah[r*40 + c0]) = *(const uint4*)hi;
        *(uint4*)(&Al[r*40 + c0]) = *(const uint4*)lo;
      }
      *(uint4*)(&Bh[r*40 + c0]) = *(const uint4*)(&wh[(size_t)(colbase + r)*512 + k0 + c0]);
      *(uint4*)(&Bl[r*40 + c0]) = *(const uint4*)(&wl[(size_t)(colbase + r)*512 + k0 + c0]);
    }
    __syncthreads();
    bf16x8 ah[4], al[4], bh8[4], bl8[4];
    #pragma unroll
    for (int m = 0; m < 4; m++) {
      const int off = (wm*64 + m*16 + (l & 15))*40 + (l >> 4)*8;
      ah[m] = *(const bf16x8*)(&Ah[off]);
      al[m] = *(const bf16x8*)(&Al[off]);
    }
    #pragma unroll
    for (int n = 0; n < 4; n++) {
      const int off = (wn*64 + n*16 + (l & 15))*40 + (l >> 4)*8;
      bh8[n] = *(const bf16x8*)(&Bh[off]);
      bl8[n] = *(const bf16x8*)(&Bl[off]);
    }
    #pragma unroll
    for (int m = 0; m < 4; m++)
      #pragma unroll
      for (int n = 0; n < 4; n++) {
        acc[m][n] = __builtin_amdgcn_mfma_f32_16x16x32_bf16(ah[m], bh8[n], acc[m][n], 0, 0, 0);
        acc[m][n] = __builtin_amdgcn_mfma_f32_16x16x32_bf16(ah[m], bl8[n], acc[m][n], 0, 0, 0);
        acc[m][n] = __builtin_amdgcn_mfma_f32_16x16x32_bf16(al[m], bh8[n], acc[m][n], 0, 0, 0);
      }
  }

  if (MODE == 0 || mat == 1) {
    // direct f32 writes: each (m,n,j) slice covers aligned 64B row segments
    const float* bias_p = (MODE == 0) ? bq : bk;
    float* dst = (MODE == 0) ? qf : kf;
    #pragma unroll
    for (int n = 0; n < 4; n++) {
      const int wi = (colbase & 511) + wn*64 + n*16 + (l & 15);
      const int hh = wi >> 6, d = wi & 63;
      const float bias = bias_p[wi];
      #pragma unroll
      for (int m = 0; m < 4; m++) {
        const int rb = rowbase + wm*64 + m*16 + ((l >> 4) << 2);
        const int b  = rb >> 12, nr = rb & 4095;
        #pragma unroll
        for (int j = 0; j < 4; j++)
          dst[((size_t)(b*8 + hh)*NS + nr + j)*ND + d] = acc[m][n][j] + bias;
      }
    }
    if (MODE == 1 && kb16) {
      // kb16 via LDS: stage [128 row][136 col] bf16, then 128B coalesced rows
      __syncthreads();
      #pragma unroll
      for (int n = 0; n < 4; n++) {
        const int c_l = wn*64 + n*16 + (l & 15);
        const float bias = bk[(colbase & 511) + c_l];
        #pragma unroll
        for (int m = 0; m < 4; m++) {
          const int rb_l = wm*64 + m*16 + ((l >> 4) << 2);
          #pragma unroll
          for (int j = 0; j < 4; j++)
            smem[(rb_l + j)*136 + c_l] = f2bf(acc[m][n][j] + bias);
        }
      }
      __syncthreads();
      const int r2 = t >> 1, half = t & 1;
      const int hh2 = ((colbase & 511) >> 6) + half;
      const int b2 = rowbase >> 12;
      const int nr2 = rowbase & 4095;
      ushort_t* op = &kb16[((size_t)(b2*8 + hh2)*NS + nr2 + r2)*ND];
      const ushort_t* ip = &smem[r2*136 + half*64];
      #pragma unroll
      for (int cch = 0; cch < 8; cch++)
        *(uint4*)(op + cch*8) = *(const uint4*)(ip + cch*8);
    }
  } else {
    // v: LDS transpose then coalesced 128B vfT row-segment writes
    __syncthreads();                  // all MFMA LDS reads done
    #pragma unroll
    for (int n = 0; n < 4; n++) {
      const int wi_l = wn*64 + n*16 + (l & 15);
      const float bias = bv[(colbase & 511) + wi_l];
      #pragma unroll
      for (int m = 0; m < 4; m++) {
        const int nr_l = wm*64 + m*16 + ((l >> 4) << 2);
        ushort4 pk;
        pk.x = f2h(acc[m][n][0] + bias);
        pk.y = f2h(acc[m][n][1] + bias);
        pk.z = f2h(acc[m][n][2] + bias);
        pk.w = f2h(acc[m][n][3] + bias);
        *(ushort4*)(&smem[wi_l*136 + nr_l]) = pk;   // [128 wi][136] f16, padded
      }
    }
    __syncthreads();
    const int wi2 = t >> 1, half = t & 1;
    const int cim = (colbase & 511) + wi2;
    const int hh2 = cim >> 6, d2 = cim & 63;
    const int b2 = rowbase >> 12;
    const int nr2 = (rowbase & 4095) + half*64;
    ushort_t* op = &vfT[((size_t)(b2*8 + hh2)*ND + d2)*NS + nr2];
    const ushort_t* ip = &smem[wi2*136 + half*64];
    #pragma unroll
    for (int cch = 0; cch < 8; cch++)
      *(uint4*)(op + cch*8) = *(const uint4*)(ip + cch*8);
  }
}

// ---------------------------------------------------------------------------
// 3a) APPROX M from bf16 k: wave per query, 8 lanes per sample-row
// ---------------------------------------------------------------------------
__global__ __launch_bounds__(256) void k_m_approx(const float* __restrict__ qf,
                                                  const ushort_t* __restrict__ kb16,
                                                  const int* __restrict__ idxs,
                                                  float* __restrict__ Mv)
{
  __shared__ float qs[4][64];
  __shared__ int   sidx[4][48];
  const int orig = blockIdx.y * 1024 + blockIdx.x;
  const int lin  = (orig & 7) * 8192 + (orig >> 3);   // bijective XCD swizzle
  const int bh   = lin >> 10;
  const int lc   = lin & 1023;
  const int t = threadIdx.x;
  const int wv = t >> 6, lane = t & 63;
  const int l = lc*4 + wv;
  qs[wv][lane] = qf[((size_t)bh*NS + l)*ND + lane];
  for (int e = t; e < 4*NU; e += 256)
    sidx[e/NU][e%NU] = idxs[(size_t)(lc*4 + e/NU)*NU + e%NU];
  __syncthreads();
  const int g  = lane >> 3;       // sample group 0..7
  const int dq = lane & 7;        // 8 bf16 at dq*8
  const float* qp = &qs[wv][dq*8];
  float mx = -FLT_MAX, sm = 0.f;
  #pragma unroll
  for (int p = 0; p < 6; p++) {
    const int s = p*8 + g;
    const bool val = (s < NU);
    const int id = sidx[wv][val ? s : NU-1];
    uint4 ku = *(const uint4*)(&kb16[((size_t)bh*NS + id)*ND + dq*8]);
    const ushort_t* kp = (const ushort_t*)&ku;
    float p_dot = qp[0]*bf2f(kp[0]) + qp[1]*bf2f(kp[1]) + qp[2]*bf2f(kp[2]) + qp[3]*bf2f(kp[3])
                + qp[4]*bf2f(kp[4]) + qp[5]*bf2f(kp[5]) + qp[6]*bf2f(kp[6]) + qp[7]*bf2f(kp[7]);
    p_dot += __shfl_xor(p_dot, 1, 64);
    p_dot += __shfl_xor(p_dot, 2, 64);
    p_dot += __shfl_xor(p_dot, 4, 64);
    if (val) { mx = fmaxf(mx, p_dot); sm += p_dot; }
  }
  #pragma unroll
  for (int o = 8; o < 64; o <<= 1) {
    mx = fmaxf(mx, __shfl_xor(mx, o, 64));
    sm += __shfl_xor(sm, o, 64);
  }
  if (lane == 0) Mv[bh*NS + l] = mx - sm * (1.0f/(float)NS);
}

// 3b) exact M (fallback path)
__global__ __launch_bounds__(256) void k_m_exact_full(const float* __restrict__ qf,
                                                      const float* __restrict__ kf,
                                                      const int* __restrict__ idxs,
                                                      float* __restrict__ Mv)
{
  const int bh = blockIdx.y;
  const int l  = blockIdx.x*4 + (threadIdx.x >> 6);
  const int lane = threadIdx.x & 63;
  const int g  = lane >> 2;
  const int dq = lane & 3;
  const float* qrow = qf + ((size_t)bh*NS + l)*ND + dq*16;
  const float4 q0 = *(const float4*)(qrow + 0);
  const float4 q1 = *(const float4*)(qrow + 4);
  const float4 q2 = *(const float4*)(qrow + 8);
  const float4 q3 = *(const float4*)(qrow + 12);
  const float* kbase = kf + (size_t)bh*NS*ND;
  const int* ib = idxs + (size_t)l*NU;
  float mx = -FLT_MAX, sm = 0.f;
  #pragma unroll
  for (int p3 = 0; p3 < 3; p3++) {
    const int s = p3*16 + g;
    const int id = ib[s < NU ? s : NU-1];
    const float* kr = kbase + (size_t)id*ND + dq*16;
    const float4 k0 = *(const float4*)(kr + 0);
    const float4 k1 = *(const float4*)(kr + 4);
    const float4 k2 = *(const float4*)(kr + 8);
    const float4 k3 = *(const float4*)(kr + 12);
    float p = q0.x*k0.x + q0.y*k0.y + q0.z*k0.z + q0.w*k0.w
            + q1.x*k1.x + q1.y*k1.y + q1.z*k1.z + q1.w*k1.w
            + q2.x*k2.x + q2.y*k2.y + q2.z*k2.z + q2.w*k2.w
            + q3.x*k3.x + q3.y*k3.y + q3.z*k3.z + q3.w*k3.w;
    p += __shfl_xor(p, 1, 64);
    p += __shfl_xor(p, 2, 64);
    if (s < NU) { mx = fmaxf(mx, p); sm += p; }
  }
  #pragma unroll
  for (int o = 4; o < 64; o <<= 1) {
    mx = fmaxf(mx, __shfl_xor(mx, o, 64));
    sm += __shfl_xor(sm, o, 64);
  }
  if (lane == 0) Mv[bh*NS + l] = mx - sm * (1.0f/(float)NS);
}

// ---------------------------------------------------------------------------
// 4) top-NSEL per (b,h): register-cached iterative argmax
// ---------------------------------------------------------------------------
template<int NSEL, int OST>
__global__ __launch_bounds__(256) void k_topk(const float* __restrict__ Mv, int* __restrict__ dst)
{
  __shared__ float wvs[4];
  __shared__ int   wis[4];
  const int bh = blockIdx.x, t = threadIdx.x;
  const int wv = t >> 6, lane = t & 63;
  float v[16];
  #pragma unroll
  for (int j = 0; j < 16; j++) v[j] = Mv[bh*NS + j*256 + t];
  unsigned removed = 0;
  float tmax = -FLT_MAX; int tidx = 0x7fffffff;
  #pragma unroll
  for (int j = 0; j < 16; j++) {
    if (v[j] > tmax) { tmax = v[j]; tidx = j*256 + t; }
  }
  for (int it = 0; it < NSEL; it++) {
    float mv = tmax; int mi = tidx;
    #pragma unroll
    for (int o = 1; o < 64; o <<= 1) {
      float vo = __shfl_xor(mv, o, 64); int io = __shfl_xor(mi, o, 64);
      if (vo > mv || (vo == mv && io < mi)) { mv = vo; mi = io; }
    }
    if (lane == 0) { wvs[wv] = mv; wis[wv] = mi; }
    __syncthreads();
    float gv = wvs[0]; int gi = wis[0];
    #pragma unroll
    for (int k2 = 1; k2 < 4; k2++) {
      float vo = wvs[k2]; int io = wis[k2];
      if (vo > gv || (vo == gv && io < gi)) { gv = vo; gi = io; }
    }
    if (t == 0) dst[bh*OST + it] = gi;
    if ((gi & 255) == t) {       // owner invalidates and rescans its 16
      removed |= 1u << (gi >> 8);
      tmax = -FLT_MAX; tidx = 0x7fffffff;
      #pragma unroll
      for (int j = 0; j < 16; j++) {
        bool ok = ((removed >> j) & 1u) == 0u;
        if (ok && (v[j] > tmax || (v[j] == tmax && (j*256+t) < tidx))) { tmax = v[j]; tidx = j*256 + t; }
      }
    }
    __syncthreads();
  }
}

// ---------------------------------------------------------------------------
// 4b) exact M for the 64 candidates: 16 lanes per candidate
// ---------------------------------------------------------------------------
__global__ __launch_bounds__(256) void k_mexact(const float* __restrict__ qf,
                                                const float* __restrict__ kf,
                                                const int* __restrict__ idxs,
                                                const int* __restrict__ Cand,
                                                float* __restrict__ Mex)
{
  const int bh = blockIdx.y, qtr = blockIdx.x, t = threadIdx.x;
  const int c = qtr*16 + (t >> 4);
  const int dl = t & 15;                    // 4 floats at dl*4
  const int l = Cand[bh*64 + c];
  const float4 q4 = *(const float4*)(&qf[((size_t)bh*NS + l)*ND + dl*4]);
  const float* kbase = kf + (size_t)bh*NS*ND;
  const int* ib = idxs + (size_t)l*NU;
  float mx = -FLT_MAX, sm = 0.f;
  for (int s = 0; s < NU; s++) {
    const int id = ib[s];
    const float4 k4 = *(const float4*)(&kbase[(size_t)id*ND + dl*4]);
    float p = q4.x*k4.x + q4.y*k4.y + q4.z*k4.z + q4.w*k4.w;
    p += __shfl_xor(p, 1, 64);
    p += __shfl_xor(p, 2, 64);
    p += __shfl_xor(p, 4, 64);
    p += __shfl_xor(p, 8, 64);
    mx = fmaxf(mx, p);
    sm += p;
  }
  if (dl == 0) Mex[bh*64 + c] = mx - sm * (1.0f/(float)NS);
}

// 4c) exact top-45 of the 64 candidates (value desc, index asc)
__global__ void k_sel45(const float* __restrict__ Mex, const int* __restrict__ Cand,
                        int* __restrict__ Mtop)
{
  const int bh = blockIdx.x, lane = threadIdx.x;   // 64 threads
  float val = Mex[bh*64 + lane];
  const int n = Cand[bh*64 + lane];
  for (int it = 0; it < NU; it++) {
    float wv = val; int wn = n;
    #pragma unroll
    for (int o = 1; o < 64; o <<= 1) {
      float vo = __shfl_xor(wv, o, 64); int io = __shfl_xor(wn, o, 64);
      if (vo > wv || (vo == wv && io < wn)) { wv = vo; wn = io; }
    }
    if (lane == 0) Mtop[bh*NUP + it] = wn;
    if (n == wn) val = -FLT_MAX;
  }
}

// ---------------------------------------------------------------------------
// 5) Q_reduce gather -> bf16 [bh][48][64] (rows 45..47 zero)
// ---------------------------------------------------------------------------
__global__ __launch_bounds__(256) void k_qreduce(const float* __restrict__ qf,
                                                 const int* __restrict__ Mtop,
                                                 ushort_t* __restrict__ Qr)
{
  const int bh = blockIdx.x, t = threadIdx.x;
  for (int e = t; e < NUP*ND; e += 256) {
    const int u = e >> 6, d = e & 63;
    float v = 0.f;
    if (u < NU) { const int r = Mtop[bh*NUP + u]; v = qf[((size_t)bh*NS + r)*ND + d]; }
    Qr[bh*NUP*ND + e] = f2bf(v);
  }
}

// ---------------------------------------------------------------------------
// 6) scores[bh][48][4096] = bf16( 0.125 * Qr @ k^T )
//    KB=1: B frags direct bf16 loads from kb16; KB=0: convert from kf
// ---------------------------------------------------------------------------
template<int KB>
__global__ __launch_bounds__(256) void k_scores(const ushort_t* __restrict__ Qr,
                                                const float* __restrict__ kf,
                                                const ushort_t* __restrict__ kb16,
                                                ushort_t* __restrict__ scores)
{
  __shared__ __align__(16) ushort_t Ql[NUP*80];
  const int bh = blockIdx.y;
  const int n0 = blockIdx.x * 256;
  const int t = threadIdx.x, w = t >> 6, l = t & 63;
  for (int chunk = t; chunk < NUP*8; chunk += 256) {
    const int r = chunk >> 3, cp = chunk & 7;
    *(uint4*)(&Ql[r*80 + cp*8]) = *(const uint4*)(&Qr[((size_t)bh*NUP + r)*ND + cp*8]);
  }
  __syncthreads();
  f32x4 acc[3][4] = {};
  const int nw = n0 + w*64;
  #pragma unroll
  for (int ks = 0; ks < 2; ks++) {
    bf16x8 a[3], b8[4];
    #pragma unroll
    for (int m = 0; m < 3; m++)
      a[m] = *(const bf16x8*)(&Ql[(m*16 + (l & 15))*80 + (l >> 4)*8 + ks*32]);
    #pragma unroll
    for (int n = 0; n < 4; n++) {
      if constexpr (KB) {
        b8[n] = *(const bf16x8*)(&kb16[((size_t)bh*NS + nw + n*16 + (l & 15))*ND + (l >> 4)*8 + ks*32]);
      } else {
        const float* kr = &kf[((size_t)bh*NS + nw + n*16 + (l & 15))*ND + (l >> 4)*8 + ks*32];
        float4 u0 = *(const float4*)kr;
        float4 u1 = *(const float4*)(kr + 4);
        ushort_t tmp[8] = {f2bf(u0.x),f2bf(u0.y),f2bf(u0.z),f2bf(u0.w),
                           f2bf(u1.x),f2bf(u1.y),f2bf(u1.z),f2bf(u1.w)};
        b8[n] = *(const bf16x8*)tmp;
      }
    }
    #pragma unroll
    for (int m = 0; m < 3; m++)
      #pragma unroll
      for (int n = 0; n < 4; n++)
        acc[m][n] = __builtin_amdgcn_mfma_f32_16x16x32_bf16(a[m], b8[n], acc[m][n], 0, 0, 0);
  }
  #pragma unroll
  for (int m = 0; m < 3; m++)
    #pragma unroll
    for (int n = 0; n < 4; n++)
      #pragma unroll
      for (int j = 0; j < 4; j++) {
        const int row = m*16 + (l >> 4)*4 + j;
        const int col = nw + n*16 + (l & 15);
        scores[((size_t)bh*NUP + row)*NS + col] = f2bf(acc[m][n][j] * 0.125f);
      }
}

// ---------------------------------------------------------------------------
// 7) softmax: bf16 scores row -> f16 attn row, in place (u<45 only)
// ---------------------------------------------------------------------------
__global__ __launch_bounds__(256) void k_softmax(ushort_t* __restrict__ scores)
{
  __shared__ float srow[NS];
  __shared__ float red[256];
  const int bh = blockIdx.y, u = blockIdx.x, t = threadIdx.x;
  ushort_t* row = scores + ((size_t)bh*NUP + u)*NS;
  float mx = -FLT_MAX;
  for (int j = t; j < NS; j += 256) { float v = bf2f(row[j]); srow[j] = v; mx = fmaxf(mx, v); }
  red[t] = mx; __syncthreads();
  for (int s = 128; s > 0; s >>= 1) { if (t < s) red[t] = fmaxf(red[t], red[t+s]); __syncthreads(); }
  mx = red[0]; __syncthreads();
  float sm = 0.f;
  for (int j = t; j < NS; j += 256) { const float e = __expf(srow[j] - mx); srow[j] = e; sm += e; }
  red[t] = sm; __syncthreads();
  for (int s = 128; s > 0; s >>= 1) { if (t < s) red[t] += red[t+s]; __syncthreads(); }
  const float inv = 1.0f / red[0];
  for (int j = t; j < NS; j += 256) row[j] = f2h(srow[j] * inv);
}

// ---------------------------------------------------------------------------
// 8) v mean from vfT (one block per (bh,d), deterministic)
// ---------------------------------------------------------------------------
__global__ __launch_bounds__(256) void k_vmean(const ushort_t* __restrict__ vfT, float* __restrict__ vmean)
{
  __shared__ float red[256];
  const int d = blockIdx.x, bh = blockIdx.y, t = threadIdx.x;
  const ushort_t* vr = vfT + ((size_t)bh*ND + d)*NS;
  float s = 0.f;
  for (int n = t; n < NS; n += 256) s += h2f(vr[n]);
  red[t] = s; __syncthreads();
  for (int st = 128; st > 0; st >>= 1) { if (t < st) red[t] += red[t+st]; __syncthreads(); }
  if (t == 0) vmean[bh*ND + d] = red[0] * (1.0f/(float)NS);
}

// ---------------------------------------------------------------------------
// 9) PV partials via f16 MFMA: pout[bh][ch][48][64] over 8 NS-chunks of 512
// ---------------------------------------------------------------------------
__global__ __launch_bounds__(256) void k_outu(const ushort_t* __restrict__ attn,
                                              const ushort_t* __restrict__ vfT,
                                              float* __restrict__ pout)
{
  const int bh = blockIdx.y, ch = blockIdx.x;
  const int t = threadIdx.x, w = t >> 6, l = t & 63;
  if (w >= 3) return;               // 3 row-tiles of 16 (48 rows); no syncs below
  const ushort_t* ab = attn + (size_t)bh*NUP*NS;
  const ushort_t* vb = vfT + (size_t)bh*ND*NS;
  f32x4 acc[4] = {};
  const int arow = w*16 + (l & 15);
  const int koff = (l >> 4)*8;
  const int kbeg = ch*512;
  for (int kc = kbeg; kc < kbeg + 512; kc += 32) {
    uint4 au = *(const uint4*)(&ab[(size_t)arow*NS + kc + koff]);
    f16x8 a = __builtin_bit_cast(f16x8, au);
    #pragma unroll
    for (int nt = 0; nt < 4; nt++) {
      uint4 bu = *(const uint4*)(&vb[(size_t)(nt*16 + (l & 15))*NS + kc + koff]);
      f16x8 b = __builtin_bit_cast(f16x8, bu);
      acc[nt] = __builtin_amdgcn_mfma_f32_16x16x32_f16(a, b, acc[nt], 0, 0, 0);
    }
  }
  #pragma unroll
  for (int nt = 0; nt < 4; nt++)
    #pragma unroll
    for (int j = 0; j < 4; j++) {
      const int u = w*16 + (l >> 4)*4 + j;
      const int d = nt*16 + (l & 15);
      pout[(((size_t)bh*8 + ch)*NUP + u)*ND + d] = acc[nt][j];
    }
}

__global__ __launch_bounds__(256) void k_delta_fin(const float* __restrict__ pout,
                                                   const float* __restrict__ vmean,
                                                   float* __restrict__ delta)
{
  const int bh = blockIdx.x, t = threadIdx.x;
  for (int e = t; e < NUP*ND; e += 256) {
    const int u = e >> 6, d = e & 63;
    float s = 0.f;
    #pragma unroll
    for (int ch = 0; ch < 8; ch++) s += pout[(((size_t)bh*8 + ch)*NUP + u)*ND + d];
    delta[((size_t)bh*NUP + u)*ND + d] = s - vmean[bh*ND + d];
  }
}

// ---------------------------------------------------------------------------
// 10) row-id map
// ---------------------------------------------------------------------------
__global__ __launch_bounds__(256) void k_uidx_init(int* __restrict__ uidx)
{
  uidx[blockIdx.x*256 + threadIdx.x] = -1;
}

__global__ void k_scatter(const int* __restrict__ Mtop, int* __restrict__ uidx)
{
  const int bh = blockIdx.x, t = threadIdx.x;  // 64 threads
  if (t < NU) {
    const int n = Mtop[bh*NUP + t];
    const int b = bh >> 3, h = bh & 7;
    const int nprime = h*512 + (n >> 3);       // reference's reshape-without-transpose
    uidx[((size_t)b*NS + nprime)*8 + (n & 7)] = bh*NUP + t;
  }
}

// ---------------------------------------------------------------------------
// 11) corrections: corr[bh*48+u][512] = delta @ Wp[j*64:(j+1)*64, :]   (f32)
// ---------------------------------------------------------------------------
__global__ __launch_bounds__(256) void k_corr(const float* __restrict__ delta,
                                              const float* __restrict__ Wp,
                                              const int* __restrict__ Mtop,
                                              float* __restrict__ corr)
{
  __shared__ float dl[64];
  const int bh = blockIdx.y, u = blockIdx.x, t = threadIdx.x;
  const int n = Mtop[bh*NUP + u];
  const int j = n & 7;
  if (t < 64) dl[t] = delta[((size_t)bh*NUP + u)*ND + t];
  __syncthreads();
  for (int c = t; c < 512; c += 256) {
    float s = 0.f;
    #pragma unroll 8
    for (int d2 = 0; d2 < 64; d2++) s += dl[d2] * Wp[(size_t)(j*64 + d2)*512 + c];
    corr[((size_t)bh*NUP + u)*512 + c] = s;
  }
}

// ---------------------------------------------------------------------------
// 12) base rows: basep[bh][512] = (vmean tiled 8x) @ Wp + bp  (f32)
// ---------------------------------------------------------------------------
__global__ __launch_bounds__(256) void k_base(const float* __restrict__ vmean,
                                              const float* __restrict__ Wp,
                                              const float* __restrict__ bp,
                                              float* __restrict__ basep)
{
  __shared__ float vm[64];
  const int bh = blockIdx.x, t = threadIdx.x;
  if (t < 64) vm[t] = vmean[bh*ND + t];
  __syncthreads();
  for (int c = t; c < 512; c += 256) {
    float s = bp[c];
    for (int k = 0; k < 512; k++) s += vm[k & 63] * Wp[(size_t)k*512 + c];
    basep[bh*512 + c] = s;
  }
}

// ---------------------------------------------------------------------------
// 13) assemble output rows (f32)
// ---------------------------------------------------------------------------
__global__ __launch_bounds__(256) void k_assemble(const float* __restrict__ basep,
                                                  const float* __restrict__ corr,
                                                  const int* __restrict__ uidx,
                                                  float* __restrict__ out)
{
  const int b = blockIdx.y, nprime = blockIdx.x, t = threadIdx.x;
  const int h = nprime >> 9;
  const int* ui = uidx + ((size_t)b*NS + nprime)*8;
  float v0 = basep[(b*8 + h)*512 + t];
  float v1 = basep[(b*8 + h)*512 + 256 + t];
  #pragma unroll
  for (int j = 0; j < 8; j++) {
    const int id = ui[j];
    if (id >= 0) { v0 += corr[(size_t)id*512 + t]; v1 += corr[(size_t)id*512 + 256 + t]; }
  }
  const size_t o = ((size_t)b*NS + nprime)*512;
  out[o + t]       = v0;
  out[o + 256 + t] = v1;
}

// ---------------------------------------------------------------------------
extern "C" void kernel_launch(void* const* d_in, const int* in_sizes, int n_in,
                              void* d_out, int out_size, void* d_ws, size_t ws_size,
                              hipStream_t stream)
{
  (void)in_sizes; (void)n_in; (void)out_size;
  const float* x  = (const float*)d_in[0];
  const float* Wq = (const float*)d_in[1];
  const float* bq = (const float*)d_in[2];
  const float* Wk = (const float*)d_in[3];
  const float* bk = (const float*)d_in[4];
  const float* Wv = (const float*)d_in[5];
  const float* bv = (const float*)d_in[6];
  const float* Wp = (const float*)d_in[7];
  const float* bp = (const float*)d_in[8];
  const int* idxs = (const int*)d_in[9];
  float* out      = (float*)d_out;

  // base workspace carve-up; stage-2 buffers alias dead qf region
  char* w = (char*)d_ws;
  float*    qf    = (float*)(w);                    // 67,108,864  [64][4096][64] f32
  float*    kf    = (float*)(w + 67108864);         // 67,108,864
  ushort_t* vfT   = (ushort_t*)(w + 134217728);     // 33,554,432  [64][64][4096] f16
  ushort_t* wh    = (ushort_t*)(w + 167772160);     //  1,572,864
  ushort_t* wl    = (ushort_t*)(w + 169345024);     //  1,572,864
  float*    Mv    = (float*)(w + 170917888);        //  1,048,576
  int*      Mtop  = (int*)(w + 171966464);          //     12,288
  ushort_t* Qr    = (ushort_t*)(w + 171978752);     //    393,216
  float*    vmean = (float*)(w + 172371968);        //     16,384  -> 172,388,352
  // xh/xl alias the qf region (live only until the q-gemm runs):
  ushort_t* xh = (ushort_t*)(w);                    // 33,554,432
  ushort_t* xl = (ushort_t*)(w + 33554432);         // 33,554,432
  // aliases inside qf (valid only after k_qreduce):
  ushort_t* scores = (ushort_t*)(w);                // 25,165,824  [64][48][4096] bf16->f16
  float*    delta  = (float*)(w + 25165824);        //    786,432
  float*    corr   = (float*)(w + 25952256);        //  6,291,456
  int*      uidx   = (int*)(w + 32243712);          //  1,048,576
  float*    basep  = (float*)(w + 33292288);        //    131,072
  float*    pout   = (float*)(w + 33423360);        //  6,291,456  [64][8][48][64]
  // approx-M extension:
  ushort_t* kb16 = (ushort_t*)(w + 172388352);      // 33,554,432  [64][4096][64] bf16
  int*      Cand = (int*)(w + 205942784);           //     16,384  [64][64]
  float*    Mex  = (float*)(w + 205959168);         //     16,384  -> end 205,975,552
  const bool approx_ok = (ws_size >= (size_t)205975552);
  ushort_t* kb16_arg = approx_ok ? kb16 : (ushort_t*)nullptr;

  k_wsplit   <<<3072, 256, 0, stream>>>(Wq, Wk, Wv, wh, wl);
  k_xsplit   <<<16384, 256, 0, stream>>>(x, xh, xl);
  k_gemm<1>  <<<dim3(8, 256), 256, 0, stream>>>(x, xh, xl, wh, wl, bq, bk, bv, qf, kf, vfT, kb16_arg);
  k_gemm<0>  <<<dim3(4, 256), 256, 0, stream>>>(x, nullptr, nullptr, wh, wl, bq, bk, bv, qf, kf, vfT, nullptr);
  if (approx_ok) {
    k_m_approx <<<dim3(1024, 64), 256, 0, stream>>>(qf, kb16, idxs, Mv);
    k_vmean    <<<dim3(64, 64), 256, 0, stream>>>(vfT, vmean);
    k_topk<64,64> <<<64, 256, 0, stream>>>(Mv, Cand);
    k_mexact   <<<dim3(4, 64), 256, 0, stream>>>(qf, kf, idxs, Cand, Mex);
    k_sel45    <<<64, 64, 0, stream>>>(Mex, Cand, Mtop);
  } else {
    k_m_exact_full <<<dim3(1024, 64), 256, 0, stream>>>(qf, kf, idxs, Mv);
    k_vmean    <<<dim3(64, 64), 256, 0, stream>>>(vfT, vmean);
    k_topk<NU,NUP> <<<64, 256, 0, stream>>>(Mv, Mtop);
  }
  k_qreduce  <<<64, 256, 0, stream>>>(qf, Mtop, Qr);
  // qf dead from here; aliases live
  if (approx_ok) {
    k_scores<1> <<<dim3(16, 64), 256, 0, stream>>>(Qr, kf, kb16, scores);
  } else {
    k_scores<0> <<<dim3(16, 64), 256, 0, stream>>>(Qr, kf, nullptr, scores);
  }
  k_softmax  <<<dim3(45, 64), 256, 0, stream>>>(scores);
  k_outu     <<<dim3(8, 64), 256, 0, stream>>>(scores, vfT, pout);
  k_delta_fin<<<64, 256, 0, stream>>>(pout, vmean, delta);
  k_uidx_init<<<1024, 256, 0, stream>>>(uidx);
  k_scatter  <<<64, 64, 0, stream>>>(Mtop, uidx);
  k_corr     <<<dim3(45, 64), 256, 0, stream>>>(delta, Wp, Mtop, corr);
  k_base     <<<64, 256, 0, stream>>>(vmean, Wp, bp, basep);
  k_assemble <<<dim3(4096, 8), 256, 0, stream>>>(basep, corr, uidx, out);
}

// Round 9
// 571.153 us; speedup vs baseline: 1.1743x; 1.0550x over previous
//
#include <hip/hip_runtime.h>
#include <float.h>

typedef unsigned short ushort_t;
typedef short bf16x8 __attribute__((ext_vector_type(8)));     // 8 bf16 (guide-verified operand type)
typedef _Float16 f16x8 __attribute__((ext_vector_type(8)));   // 8 f16
typedef float f32x4 __attribute__((ext_vector_type(4)));

#define NS 4096
#define ND 64
#define NU 45
#define NUP 48

__device__ __forceinline__ float bf2f(ushort_t u){ return __uint_as_float(((unsigned)u)<<16); }
__device__ __forceinline__ ushort_t f2bf(float f){
  unsigned u = __float_as_uint(f);
  u += 0x7fffu + ((u>>16)&1u);   // RNE
  return (ushort_t)(u>>16);
}
__device__ __forceinline__ ushort_t f2h(float f){ _Float16 h=(_Float16)f; return __builtin_bit_cast(ushort_t, h); }
__device__ __forceinline__ float h2f(ushort_t u){ return (float)__builtin_bit_cast(_Float16, u); }

// ---------------------------------------------------------------------------
// 1) W split+transpose: Wq|Wk|Wv f32 [k][n] -> wh,wl bf16 [1536 n][512 k]
// ---------------------------------------------------------------------------
__global__ __launch_bounds__(256) void k_wsplit(const float* __restrict__ Wq,
                                                const float* __restrict__ Wk,
                                                const float* __restrict__ Wv,
                                                ushort_t* __restrict__ wh,
                                                ushort_t* __restrict__ wl)
{
  int i = blockIdx.x*256 + threadIdx.x;     // < 1536*512
  int c = i >> 9, k = i & 511;
  const float* W = (c < 512) ? Wq : (c < 1024 ? Wk : Wv);
  float v = W[k*512 + (c & 511)];
  ushort_t h = f2bf(v);
  wh[i] = h;
  wl[i] = f2bf(v - bf2f(h));
}

// ---------------------------------------------------------------------------
// 2) QKV projection (A and B staged in LDS; inline x hi/lo convert)
//    MODE 0: q, 1-term bf16 (4 col-tiles)  -> qb16 bf16 [bh][n][64] via LDS
//    MODE 1: kv, 3-term f32-faithful (8 col-tiles)
//            -> kf f32 (+kb16 bf16 via LDS); v f16 TRANSPOSED via LDS
// ---------------------------------------------------------------------------
template<int MODE>
__global__ __launch_bounds__(256) void k_gemm(
    const float* __restrict__ x,
    const ushort_t* __restrict__ wh, const ushort_t* __restrict__ wl,
    const float* __restrict__ bq, const float* __restrict__ bk, const float* __restrict__ bv,
    float* __restrict__ kf, ushort_t* __restrict__ vfT,
    ushort_t* __restrict__ kb16, ushort_t* __restrict__ qb16)
{
  __shared__ __align__(16) ushort_t smem[20480];      // 40 KiB stage / 34.8 KiB epilogue transpose
  ushort_t* Ah = smem;
  ushort_t* Al = smem + 5120;                          // MODE1 only
  ushort_t* Bh = smem + (MODE == 1 ? 10240 : 5120);
  ushort_t* Bl = smem + 15360;                         // MODE1 only
  const int nbx = (MODE == 0) ? 4 : 8;
  const int p = blockIdx.y * nbx + blockIdx.x;
  const int cx = p & 7;               // XCD slot
  const int local = p >> 3;
  const int by = cx*32 + local/nbx;   // 32 row-panels per XCD chunk
  const int bx = local % nbx;
  const int rowbase = by * 128;
  const int colbase = (MODE == 0 ? 0 : 512) + bx*128;
  const int mat = colbase >> 9;       // 0=q 1=k 2=v
  const int t = threadIdx.x;
  const int l = t & 63;
  const int w = t >> 6;
  const int wm = w >> 1, wn = w & 1;
  f32x4 acc[4][4] = {};
  const int r0 = t >> 2;              // 0..63
  const int c0 = (t & 3) * 8;         // elem offset within 32-wide K slab

  for (int k0 = 0; k0 < 512; k0 += 32) {
    __syncthreads();
    #pragma unroll
    for (int half = 0; half < 2; half++) {
      const int r = r0 + half*64;
      const float* xp = &x[(size_t)(rowbase + r)*512 + k0 + c0];
      float4 v0 = *(const float4*)xp;
      float4 v1 = *(const float4*)(xp + 4);
      ushort_t hi[8], lo[8];
      float vv[8] = {v0.x,v0.y,v0.z,v0.w,v1.x,v1.y,v1.z,v1.w};
      #pragma unroll
      for (int j = 0; j < 8; j++) {
        hi[j] = f2bf(vv[j]);
        if (MODE == 1) lo[j] = f2bf(vv[j] - bf2f(hi[j]));
      }
      *(uint4*)(&Ah[r*40 + c0]) = *(const uint4*)hi;
      if (MODE == 1) *(uint4*)(&Al[r*40 + c0]) = *(const uint4*)lo;
      *(uint4*)(&Bh[r*40 + c0]) = *(const uint4*)(&wh[(size_t)(colbase + r)*512 + k0 + c0]);
      if (MODE == 1) *(uint4*)(&Bl[r*40 + c0]) = *(const uint4*)(&wl[(size_t)(colbase + r)*512 + k0 + c0]);
    }
    __syncthreads();
    bf16x8 ah[4], al[4], bh8[4], bl8[4];
    #pragma unroll
    for (int m = 0; m < 4; m++) {
      const int off = (wm*64 + m*16 + (l & 15))*40 + (l >> 4)*8;
      ah[m] = *(const bf16x8*)(&Ah[off]);
      if (MODE == 1) al[m] = *(const bf16x8*)(&Al[off]);
    }
    #pragma unroll
    for (int n = 0; n < 4; n++) {
      const int off = (wn*64 + n*16 + (l & 15))*40 + (l >> 4)*8;
      bh8[n] = *(const bf16x8*)(&Bh[off]);
      if (MODE == 1) bl8[n] = *(const bf16x8*)(&Bl[off]);
    }
    #pragma unroll
    for (int m = 0; m < 4; m++)
      #pragma unroll
      for (int n = 0; n < 4; n++) {
        acc[m][n] = __builtin_amdgcn_mfma_f32_16x16x32_bf16(ah[m], bh8[n], acc[m][n], 0, 0, 0);
        if (MODE == 1) {
          acc[m][n] = __builtin_amdgcn_mfma_f32_16x16x32_bf16(ah[m], bl8[n], acc[m][n], 0, 0, 0);
          acc[m][n] = __builtin_amdgcn_mfma_f32_16x16x32_bf16(al[m], bh8[n], acc[m][n], 0, 0, 0);
        }
      }
  }

  if (MODE == 1 && mat == 2) {
    // v: LDS transpose then coalesced 128B vfT row-segment writes
    __syncthreads();
    #pragma unroll
    for (int n = 0; n < 4; n++) {
      const int wi_l = wn*64 + n*16 + (l & 15);
      const float bias = bv[(colbase & 511) + wi_l];
      #pragma unroll
      for (int m = 0; m < 4; m++) {
        const int nr_l = wm*64 + m*16 + ((l >> 4) << 2);
        ushort4 pk;
        pk.x = f2h(acc[m][n][0] + bias);
        pk.y = f2h(acc[m][n][1] + bias);
        pk.z = f2h(acc[m][n][2] + bias);
        pk.w = f2h(acc[m][n][3] + bias);
        *(ushort4*)(&smem[wi_l*136 + nr_l]) = pk;   // [128 wi][136] f16, padded
      }
    }
    __syncthreads();
    const int wi2 = t >> 1, half = t & 1;
    const int cim = (colbase & 511) + wi2;
    const int hh2 = cim >> 6, d2 = cim & 63;
    const int b2 = rowbase >> 12;
    const int nr2 = (rowbase & 4095) + half*64;
    ushort_t* op = &vfT[((size_t)(b2*8 + hh2)*ND + d2)*NS + nr2];
    const ushort_t* ip = &smem[wi2*136 + half*64];
    #pragma unroll
    for (int cch = 0; cch < 8; cch++)
      *(uint4*)(op + cch*8) = *(const uint4*)(ip + cch*8);
    return;
  }

  if (MODE == 1) {
    // k: direct f32 writes (aligned 64B row segments)
    #pragma unroll
    for (int n = 0; n < 4; n++) {
      const int wi = (colbase & 511) + wn*64 + n*16 + (l & 15);
      const int hh = wi >> 6, d = wi & 63;
      const float bias = bk[wi];
      #pragma unroll
      for (int m = 0; m < 4; m++) {
        const int rb = rowbase + wm*64 + m*16 + ((l >> 4) << 2);
        const int b  = rb >> 12, nr = rb & 4095;
        #pragma unroll
        for (int j = 0; j < 4; j++)
          kf[((size_t)(b*8 + hh)*NS + nr + j)*ND + d] = acc[m][n][j] + bias;
      }
    }
  }
  // bf16 [bh][n][64] output via LDS: kb16 (MODE1 k) or qb16 (MODE0)
  {
    ushort_t* obuf = (MODE == 0) ? qb16 : kb16;
    const float* bias_p = (MODE == 0) ? bq : bk;
    __syncthreads();
    #pragma unroll
    for (int n = 0; n < 4; n++) {
      const int c_l = wn*64 + n*16 + (l & 15);
      const float bias = bias_p[(colbase & 511) + c_l];
      #pragma unroll
      for (int m = 0; m < 4; m++) {
        const int rb_l = wm*64 + m*16 + ((l >> 4) << 2);
        #pragma unroll
        for (int j = 0; j < 4; j++)
          smem[(rb_l + j)*136 + c_l] = f2bf(acc[m][n][j] + bias);
      }
    }
    __syncthreads();
    const int r2 = t >> 1, half = t & 1;
    const int hh2 = ((colbase & 511) >> 6) + half;
    const int b2 = rowbase >> 12;
    const int nr2 = rowbase & 4095;
    ushort_t* op = &obuf[((size_t)(b2*8 + hh2)*NS + nr2 + r2)*ND];
    const ushort_t* ip = &smem[r2*136 + half*64];
    #pragma unroll
    for (int cch = 0; cch < 8; cch++)
      *(uint4*)(op + cch*8) = *(const uint4*)(ip + cch*8);
  }
}

// ---------------------------------------------------------------------------
// 3) APPROX M from bf16 q,k: wave per query, 8 lanes per sample-row
// ---------------------------------------------------------------------------
__global__ __launch_bounds__(256) void k_m_approx(const ushort_t* __restrict__ qb16,
                                                  const ushort_t* __restrict__ kb16,
                                                  const int* __restrict__ idxs,
                                                  float* __restrict__ Mv)
{
  __shared__ float qs[4][64];
  __shared__ int   sidx[4][48];
  const int orig = blockIdx.y * 1024 + blockIdx.x;
  const int lin  = (orig & 7) * 8192 + (orig >> 3);   // bijective XCD swizzle
  const int bh   = lin >> 10;
  const int lc   = lin & 1023;
  const int t = threadIdx.x;
  const int wv = t >> 6, lane = t & 63;
  const int l = lc*4 + wv;
  qs[wv][lane] = bf2f(qb16[((size_t)bh*NS + l)*ND + lane]);
  for (int e = t; e < 4*NU; e += 256)
    sidx[e/NU][e%NU] = idxs[(size_t)(lc*4 + e/NU)*NU + e%NU];
  __syncthreads();
  const int g  = lane >> 3;       // sample group 0..7
  const int dq = lane & 7;        // 8 bf16 at dq*8
  const float* qp = &qs[wv][dq*8];
  float mx = -FLT_MAX, sm = 0.f;
  #pragma unroll
  for (int p = 0; p < 6; p++) {
    const int s = p*8 + g;
    const bool val = (s < NU);
    const int id = sidx[wv][val ? s : NU-1];
    uint4 ku = *(const uint4*)(&kb16[((size_t)bh*NS + id)*ND + dq*8]);
    const ushort_t* kp = (const ushort_t*)&ku;
    float p_dot = qp[0]*bf2f(kp[0]) + qp[1]*bf2f(kp[1]) + qp[2]*bf2f(kp[2]) + qp[3]*bf2f(kp[3])
                + qp[4]*bf2f(kp[4]) + qp[5]*bf2f(kp[5]) + qp[6]*bf2f(kp[6]) + qp[7]*bf2f(kp[7]);
    p_dot += __shfl_xor(p_dot, 1, 64);
    p_dot += __shfl_xor(p_dot, 2, 64);
    p_dot += __shfl_xor(p_dot, 4, 64);
    if (val) { mx = fmaxf(mx, p_dot); sm += p_dot; }
  }
  #pragma unroll
  for (int o = 8; o < 64; o <<= 1) {
    mx = fmaxf(mx, __shfl_xor(mx, o, 64));
    sm += __shfl_xor(sm, o, 64);
  }
  if (lane == 0) Mv[bh*NS + l] = mx - sm * (1.0f/(float)NS);
}

// ---------------------------------------------------------------------------
// 4) top-64 per (b,h): register-cached iterative argmax
// ---------------------------------------------------------------------------
template<int NSEL, int OST>
__global__ __launch_bounds__(256) void k_topk(const float* __restrict__ Mv, int* __restrict__ dst)
{
  __shared__ float wvs[4];
  __shared__ int   wis[4];
  const int bh = blockIdx.x, t = threadIdx.x;
  const int wv = t >> 6, lane = t & 63;
  float v[16];
  #pragma unroll
  for (int j = 0; j < 16; j++) v[j] = Mv[bh*NS + j*256 + t];
  unsigned removed = 0;
  float tmax = -FLT_MAX; int tidx = 0x7fffffff;
  #pragma unroll
  for (int j = 0; j < 16; j++) {
    if (v[j] > tmax) { tmax = v[j]; tidx = j*256 + t; }
  }
  for (int it = 0; it < NSEL; it++) {
    float mv = tmax; int mi = tidx;
    #pragma unroll
    for (int o = 1; o < 64; o <<= 1) {
      float vo = __shfl_xor(mv, o, 64); int io = __shfl_xor(mi, o, 64);
      if (vo > mv || (vo == mv && io < mi)) { mv = vo; mi = io; }
    }
    if (lane == 0) { wvs[wv] = mv; wis[wv] = mi; }
    __syncthreads();
    float gv = wvs[0]; int gi = wis[0];
    #pragma unroll
    for (int k2 = 1; k2 < 4; k2++) {
      float vo = wvs[k2]; int io = wis[k2];
      if (vo > gv || (vo == gv && io < gi)) { gv = vo; gi = io; }
    }
    if (t == 0) dst[bh*OST + it] = gi;
    if ((gi & 255) == t) {       // owner invalidates and rescans its 16
      removed |= 1u << (gi >> 8);
      tmax = -FLT_MAX; tidx = 0x7fffffff;
      #pragma unroll
      for (int j = 0; j < 16; j++) {
        bool ok = ((removed >> j) & 1u) == 0u;
        if (ok && (v[j] > tmax || (v[j] == tmax && (j*256+t) < tidx))) { tmax = v[j]; tidx = j*256 + t; }
      }
    }
    __syncthreads();
  }
}

// ---------------------------------------------------------------------------
// 4b) exact q for the 64 candidates: 3-term split-bf16 (same math as old qf)
//     qex[bh][cand][64] f32; one block per bh (4 waves x 16 cands x 64 cols)
// ---------------------------------------------------------------------------
__global__ __launch_bounds__(256) void k_qexact(const float* __restrict__ x,
                                                const ushort_t* __restrict__ wh,
                                                const ushort_t* __restrict__ wl,
                                                const float* __restrict__ bq,
                                                const int* __restrict__ Cand,
                                                float* __restrict__ qex)
{
  const int bh = blockIdx.x, t = threadIdx.x;
  const int wv = t >> 6, l = t & 63;
  const int b = bh >> 3, h = bh & 7;
  const int cand = 16*wv + (l & 15);
  const int n = Cand[bh*64 + cand];
  const float* xr = x + ((size_t)b*NS + n)*512 + (l >> 4)*8;
  f32x4 acc[4] = {};
  for (int k0 = 0; k0 < 512; k0 += 32) {
    float4 v0 = *(const float4*)(xr + k0);
    float4 v1 = *(const float4*)(xr + k0 + 4);
    ushort_t hi[8], lo[8];
    float vv[8] = {v0.x,v0.y,v0.z,v0.w,v1.x,v1.y,v1.z,v1.w};
    #pragma unroll
    for (int j = 0; j < 8; j++) {
      hi[j] = f2bf(vv[j]);
      lo[j] = f2bf(vv[j] - bf2f(hi[j]));
    }
    bf16x8 ah = *(const bf16x8*)hi;
    bf16x8 al = *(const bf16x8*)lo;
    #pragma unroll
    for (int nt = 0; nt < 4; nt++) {
      const size_t boff = (size_t)(h*64 + nt*16 + (l & 15))*512 + k0 + (l >> 4)*8;
      bf16x8 bh8 = *(const bf16x8*)(&wh[boff]);
      bf16x8 bl8 = *(const bf16x8*)(&wl[boff]);
      acc[nt] = __builtin_amdgcn_mfma_f32_16x16x32_bf16(ah, bh8, acc[nt], 0, 0, 0);
      acc[nt] = __builtin_amdgcn_mfma_f32_16x16x32_bf16(ah, bl8, acc[nt], 0, 0, 0);
      acc[nt] = __builtin_amdgcn_mfma_f32_16x16x32_bf16(al, bh8, acc[nt], 0, 0, 0);
    }
  }
  #pragma unroll
  for (int nt = 0; nt < 4; nt++)
    #pragma unroll
    for (int j = 0; j < 4; j++) {
      const int cand_o = 16*wv + (l >> 4)*4 + j;
      const int d_o = nt*16 + (l & 15);
      qex[((size_t)bh*64 + cand_o)*ND + d_o] = acc[nt][j] + bq[h*64 + d_o];
    }
}

// ---------------------------------------------------------------------------
// 4c) exact M for the 64 candidates: 16 lanes per candidate (reads qex, kf)
// ---------------------------------------------------------------------------
__global__ __launch_bounds__(256) void k_mexact(const float* __restrict__ qex,
                                                const float* __restrict__ kf,
                                                const int* __restrict__ idxs,
                                                const int* __restrict__ Cand,
                                                float* __restrict__ Mex)
{
  const int bh = blockIdx.y, qtr = blockIdx.x, t = threadIdx.x;
  const int c = qtr*16 + (t >> 4);
  const int dl = t & 15;                    // 4 floats at dl*4
  const int l = Cand[bh*64 + c];
  const float4 q4 = *(const float4*)(&qex[((size_t)bh*64 + c)*ND + dl*4]);
  const float* kbase = kf + (size_t)bh*NS*ND;
  const int* ib = idxs + (size_t)l*NU;
  float mx = -FLT_MAX, sm = 0.f;
  for (int s = 0; s < NU; s++) {
    const int id = ib[s];
    const float4 k4 = *(const float4*)(&kbase[(size_t)id*ND + dl*4]);
    float p = q4.x*k4.x + q4.y*k4.y + q4.z*k4.z + q4.w*k4.w;
    p += __shfl_xor(p, 1, 64);
    p += __shfl_xor(p, 2, 64);
    p += __shfl_xor(p, 4, 64);
    p += __shfl_xor(p, 8, 64);
    mx = fmaxf(mx, p);
    sm += p;
  }
  if (dl == 0) Mex[bh*64 + c] = mx - sm * (1.0f/(float)NS);
}

// 4d) exact top-45 of the 64 candidates (value desc, index asc); keeps slot
__global__ void k_sel45(const float* __restrict__ Mex, const int* __restrict__ Cand,
                        int* __restrict__ Mtop, int* __restrict__ MtopSlot)
{
  const int bh = blockIdx.x, lane = threadIdx.x;   // 64 threads
  float val = Mex[bh*64 + lane];
  const int n = Cand[bh*64 + lane];
  const int slot = lane;
  for (int it = 0; it < NU; it++) {
    float wv = val; int wn = n; int ws = slot;
    #pragma unroll
    for (int o = 1; o < 64; o <<= 1) {
      float vo = __shfl_xor(wv, o, 64); int io = __shfl_xor(wn, o, 64); int so = __shfl_xor(ws, o, 64);
      if (vo > wv || (vo == wv && io < wn)) { wv = vo; wn = io; ws = so; }
    }
    if (lane == 0) { Mtop[bh*NUP + it] = wn; MtopSlot[bh*NUP + it] = ws; }
    if (n == wn) val = -FLT_MAX;
  }
}

// ---------------------------------------------------------------------------
// 5) Q_reduce gather from qex -> bf16 [bh][48][64] (rows 45..47 zero)
// ---------------------------------------------------------------------------
__global__ __launch_bounds__(256) void k_qreduce(const float* __restrict__ qex,
                                                 const int* __restrict__ MtopSlot,
                                                 ushort_t* __restrict__ Qr)
{
  const int bh = blockIdx.x, t = threadIdx.x;
  for (int e = t; e < NUP*ND; e += 256) {
    const int u = e >> 6, d = e & 63;
    float v = 0.f;
    if (u < NU) { const int s = MtopSlot[bh*NUP + u]; v = qex[((size_t)bh*64 + s)*ND + d]; }
    Qr[bh*NUP*ND + e] = f2bf(v);
  }
}

// ---------------------------------------------------------------------------
// 6) scores[bh][48][4096] = bf16( 0.125 * Qr @ k^T ), B direct from kb16
// ---------------------------------------------------------------------------
__global__ __launch_bounds__(256) void k_scores(const ushort_t* __restrict__ Qr,
                                                const ushort_t* __restrict__ kb16,
                                                ushort_t* __restrict__ scores)
{
  __shared__ __align__(16) ushort_t Ql[NUP*80];
  const int bh = blockIdx.y;
  const int n0 = blockIdx.x * 256;
  const int t = threadIdx.x, w = t >> 6, l = t & 63;
  for (int chunk = t; chunk < NUP*8; chunk += 256) {
    const int r = chunk >> 3, cp = chunk & 7;
    *(uint4*)(&Ql[r*80 + cp*8]) = *(const uint4*)(&Qr[((size_t)bh*NUP + r)*ND + cp*8]);
  }
  __syncthreads();
  f32x4 acc[3][4] = {};
  const int nw = n0 + w*64;
  #pragma unroll
  for (int ks = 0; ks < 2; ks++) {
    bf16x8 a[3], b8[4];
    #pragma unroll
    for (int m = 0; m < 3; m++)
      a[m] = *(const bf16x8*)(&Ql[(m*16 + (l & 15))*80 + (l >> 4)*8 + ks*32]);
    #pragma unroll
    for (int n = 0; n < 4; n++)
      b8[n] = *(const bf16x8*)(&kb16[((size_t)bh*NS + nw + n*16 + (l & 15))*ND + (l >> 4)*8 + ks*32]);
    #pragma unroll
    for (int m = 0; m < 3; m++)
      #pragma unroll
      for (int n = 0; n < 4; n++)
        acc[m][n] = __builtin_amdgcn_mfma_f32_16x16x32_bf16(a[m], b8[n], acc[m][n], 0, 0, 0);
  }
  #pragma unroll
  for (int m = 0; m < 3; m++)
    #pragma unroll
    for (int n = 0; n < 4; n++)
      #pragma unroll
      for (int j = 0; j < 4; j++) {
        const int row = m*16 + (l >> 4)*4 + j;
        const int col = nw + n*16 + (l & 15);
        scores[((size_t)bh*NUP + row)*NS + col] = f2bf(acc[m][n][j] * 0.125f);
      }
}

// ---------------------------------------------------------------------------
// 7) softmax: bf16 scores row -> f16 attn row, in place (u<45 only)
// ---------------------------------------------------------------------------
__global__ __launch_bounds__(256) void k_softmax(ushort_t* __restrict__ scores)
{
  __shared__ float srow[NS];
  __shared__ float red[256];
  const int bh = blockIdx.y, u = blockIdx.x, t = threadIdx.x;
  ushort_t* row = scores + ((size_t)bh*NUP + u)*NS;
  float mx = -FLT_MAX;
  for (int j = t; j < NS; j += 256) { float v = bf2f(row[j]); srow[j] = v; mx = fmaxf(mx, v); }
  red[t] = mx; __syncthreads();
  for (int s = 128; s > 0; s >>= 1) { if (t < s) red[t] = fmaxf(red[t], red[t+s]); __syncthreads(); }
  mx = red[0]; __syncthreads();
  float sm = 0.f;
  for (int j = t; j < NS; j += 256) { const float e = __expf(srow[j] - mx); srow[j] = e; sm += e; }
  red[t] = sm; __syncthreads();
  for (int s = 128; s > 0; s >>= 1) { if (t < s) red[t] += red[t+s]; __syncthreads(); }
  const float inv = 1.0f / red[0];
  for (int j = t; j < NS; j += 256) row[j] = f2h(srow[j] * inv);
}

// ---------------------------------------------------------------------------
// 8) v mean from vfT (one block per (bh,d), deterministic)
// ---------------------------------------------------------------------------
__global__ __launch_bounds__(256) void k_vmean(const ushort_t* __restrict__ vfT, float* __restrict__ vmean)
{
  __shared__ float red[256];
  const int d = blockIdx.x, bh = blockIdx.y, t = threadIdx.x;
  const ushort_t* vr = vfT + ((size_t)bh*ND + d)*NS;
  float s = 0.f;
  for (int n = t; n < NS; n += 256) s += h2f(vr[n]);
  red[t] = s; __syncthreads();
  for (int st = 128; st > 0; st >>= 1) { if (t < st) red[t] += red[t+st]; __syncthreads(); }
  if (t == 0) vmean[bh*ND + d] = red[0] * (1.0f/(float)NS);
}

// ---------------------------------------------------------------------------
// 9) PV partials via f16 MFMA: pout[bh][ch][48][64] over 8 NS-chunks of 512
// ---------------------------------------------------------------------------
__global__ __launch_bounds__(256) void k_outu(const ushort_t* __restrict__ attn,
                                              const ushort_t* __restrict__ vfT,
                                              float* __restrict__ pout)
{
  const int bh = blockIdx.y, ch = blockIdx.x;
  const int t = threadIdx.x, w = t >> 6, l = t & 63;
  if (w >= 3) return;               // 3 row-tiles of 16 (48 rows); no syncs below
  const ushort_t* ab = attn + (size_t)bh*NUP*NS;
  const ushort_t* vb = vfT + (size_t)bh*ND*NS;
  f32x4 acc[4] = {};
  const int arow = w*16 + (l & 15);
  const int koff = (l >> 4)*8;
  const int kbeg = ch*512;
  for (int kc = kbeg; kc < kbeg + 512; kc += 32) {
    uint4 au = *(const uint4*)(&ab[(size_t)arow*NS + kc + koff]);
    f16x8 a = __builtin_bit_cast(f16x8, au);
    #pragma unroll
    for (int nt = 0; nt < 4; nt++) {
      uint4 bu = *(const uint4*)(&vb[(size_t)(nt*16 + (l & 15))*NS + kc + koff]);
      f16x8 b = __builtin_bit_cast(f16x8, bu);
      acc[nt] = __builtin_amdgcn_mfma_f32_16x16x32_f16(a, b, acc[nt], 0, 0, 0);
    }
  }
  #pragma unroll
  for (int nt = 0; nt < 4; nt++)
    #pragma unroll
    for (int j = 0; j < 4; j++) {
      const int u = w*16 + (l >> 4)*4 + j;
      const int d = nt*16 + (l & 15);
      pout[(((size_t)bh*8 + ch)*NUP + u)*ND + d] = acc[nt][j];
    }
}

__global__ __launch_bounds__(256) void k_delta_fin(const float* __restrict__ pout,
                                                   const float* __restrict__ vmean,
                                                   float* __restrict__ delta)
{
  const int bh = blockIdx.x, t = threadIdx.x;
  for (int e = t; e < NUP*ND; e += 256) {
    const int u = e >> 6, d = e & 63;
    float s = 0.f;
    #pragma unroll
    for (int ch = 0; ch < 8; ch++) s += pout[(((size_t)bh*8 + ch)*NUP + u)*ND + d];
    delta[((size_t)bh*NUP + u)*ND + d] = s - vmean[bh*ND + d];
  }
}

// ---------------------------------------------------------------------------
// 10) row-id map
// ---------------------------------------------------------------------------
__global__ __launch_bounds__(256) void k_uidx_init(int* __restrict__ uidx)
{
  uidx[blockIdx.x*256 + threadIdx.x] = -1;
}

__global__ void k_scatter(const int* __restrict__ Mtop, int* __restrict__ uidx)
{
  const int bh = blockIdx.x, t = threadIdx.x;  // 64 threads
  if (t < NU) {
    const int n = Mtop[bh*NUP + t];
    const int b = bh >> 3, h = bh & 7;
    const int nprime = h*512 + (n >> 3);       // reference's reshape-without-transpose
    uidx[((size_t)b*NS + nprime)*8 + (n & 7)] = bh*NUP + t;
  }
}

// ---------------------------------------------------------------------------
// 11) corrections: corr[bh*48+u][512] = delta @ Wp[j*64:(j+1)*64, :]   (f32)
// ---------------------------------------------------------------------------
__global__ __launch_bounds__(256) void k_corr(const float* __restrict__ delta,
                                              const float* __restrict__ Wp,
                                              const int* __restrict__ Mtop,
                                              float* __restrict__ corr)
{
  __shared__ float dl[64];
  const int bh = blockIdx.y, u = blockIdx.x, t = threadIdx.x;
  const int n = Mtop[bh*NUP + u];
  const int j = n & 7;
  if (t < 64) dl[t] = delta[((size_t)bh*NUP + u)*ND + t];
  __syncthreads();
  for (int c = t; c < 512; c += 256) {
    float s = 0.f;
    #pragma unroll 8
    for (int d2 = 0; d2 < 64; d2++) s += dl[d2] * Wp[(size_t)(j*64 + d2)*512 + c];
    corr[((size_t)bh*NUP + u)*512 + c] = s;
  }
}

// ---------------------------------------------------------------------------
// 12) Wpsum[d2][c] = sum_j Wp[j*64+d2][c]; base rows from Wpsum
// ---------------------------------------------------------------------------
__global__ __launch_bounds__(256) void k_wpsum(const float* __restrict__ Wp,
                                               float* __restrict__ Wpsum)
{
  int i = blockIdx.x*256 + threadIdx.x;   // < 64*512
  int d2 = i >> 9, c = i & 511;
  float s = 0.f;
  #pragma unroll
  for (int j = 0; j < 8; j++) s += Wp[(size_t)(j*64 + d2)*512 + c];
  Wpsum[i] = s;
}

__global__ __launch_bounds__(256) void k_base(const float* __restrict__ vmean,
                                              const float* __restrict__ Wpsum,
                                              const float* __restrict__ bp,
                                              float* __restrict__ basep)
{
  __shared__ float vm[64];
  const int bh = blockIdx.x, t = threadIdx.x;
  if (t < 64) vm[t] = vmean[bh*ND + t];
  __syncthreads();
  for (int c = t; c < 512; c += 256) {
    float s = bp[c];
    #pragma unroll 8
    for (int d2 = 0; d2 < 64; d2++) s += vm[d2] * Wpsum[d2*512 + c];
    basep[bh*512 + c] = s;
  }
}

// ---------------------------------------------------------------------------
// 13) assemble output rows (f32)
// ---------------------------------------------------------------------------
__global__ __launch_bounds__(256) void k_assemble(const float* __restrict__ basep,
                                                  const float* __restrict__ corr,
                                                  const int* __restrict__ uidx,
                                                  float* __restrict__ out)
{
  const int b = blockIdx.y, nprime = blockIdx.x, t = threadIdx.x;
  const int h = nprime >> 9;
  const int* ui = uidx + ((size_t)b*NS + nprime)*8;
  float v0 = basep[(b*8 + h)*512 + t];
  float v1 = basep[(b*8 + h)*512 + 256 + t];
  #pragma unroll
  for (int j = 0; j < 8; j++) {
    const int id = ui[j];
    if (id >= 0) { v0 += corr[(size_t)id*512 + t]; v1 += corr[(size_t)id*512 + 256 + t]; }
  }
  const size_t o = ((size_t)b*NS + nprime)*512;
  out[o + t]       = v0;
  out[o + 256 + t] = v1;
}

// ---------------------------------------------------------------------------
extern "C" void kernel_launch(void* const* d_in, const int* in_sizes, int n_in,
                              void* d_out, int out_size, void* d_ws, size_t ws_size,
                              hipStream_t stream)
{
  (void)in_sizes; (void)n_in; (void)out_size; (void)ws_size;
  const float* x  = (const float*)d_in[0];
  const float* Wq = (const float*)d_in[1];
  const float* bq = (const float*)d_in[2];
  const float* Wk = (const float*)d_in[3];
  const float* bk = (const float*)d_in[4];
  const float* Wv = (const float*)d_in[5];
  const float* bv = (const float*)d_in[6];
  const float* Wp = (const float*)d_in[7];
  const float* bp = (const float*)d_in[8];
  const int* idxs = (const int*)d_in[9];
  float* out      = (float*)d_out;

  // workspace carve-up (~174 MB live peak; ws >= 206 MB established)
  char* w = (char*)d_ws;
  float*    kf    = (float*)(w);                    // 67,108,864  [64][4096][64] f32 (dead after k_mexact)
  ushort_t* vfT   = (ushort_t*)(w + 67108864);      // 33,554,432  [64][64][4096] f16
  ushort_t* kb16  = (ushort_t*)(w + 100663296);     // 33,554,432  [64][4096][64] bf16
  ushort_t* qb16  = (ushort_t*)(w + 134217728);     // 33,554,432  [64][4096][64] bf16
  ushort_t* wh    = (ushort_t*)(w + 167772160);     //  1,572,864
  ushort_t* wl    = (ushort_t*)(w + 169345024);     //  1,572,864
  float*    Mv    = (float*)(w + 170917888);        //  1,048,576
  int*      Mtop  = (int*)(w + 171966464);          //     12,288
  int*      MtopSlot = (int*)(w + 171978752);       //     12,288
  int*      Cand  = (int*)(w + 171991040);          //     16,384
  float*    Mex   = (float*)(w + 172007424);        //     16,384
  float*    vmean = (float*)(w + 172023808);        //     16,384
  ushort_t* Qr    = (ushort_t*)(w + 172040192);     //    393,216
  float*    qex   = (float*)(w + 172433408);        //  1,048,576  [64][64][64] f32
  float*    Wpsum = (float*)(w + 173481984);        //    131,072  -> end 173,613,056
  // tail aliases over the dead kf region (valid after k_mexact):
  ushort_t* scores = (ushort_t*)(w);                // 25,165,824
  float*    delta  = (float*)(w + 25165824);        //    786,432
  float*    corr   = (float*)(w + 25952256);        //  6,291,456
  int*      uidx   = (int*)(w + 32243712);          //  1,048,576
  float*    basep  = (float*)(w + 33292288);        //    131,072
  float*    pout   = (float*)(w + 33423360);        //  6,291,456  -> 39,714,816

  k_wsplit   <<<3072, 256, 0, stream>>>(Wq, Wk, Wv, wh, wl);
  k_gemm<1>  <<<dim3(8, 256), 256, 0, stream>>>(x, wh, wl, bq, bk, bv, kf, vfT, kb16, nullptr);
  k_gemm<0>  <<<dim3(4, 256), 256, 0, stream>>>(x, wh, wl, bq, bk, bv, nullptr, nullptr, nullptr, qb16);
  k_wpsum    <<<128, 256, 0, stream>>>(Wp, Wpsum);
  k_m_approx <<<dim3(1024, 64), 256, 0, stream>>>(qb16, kb16, idxs, Mv);
  k_vmean    <<<dim3(64, 64), 256, 0, stream>>>(vfT, vmean);
  k_topk<64,64> <<<64, 256, 0, stream>>>(Mv, Cand);
  k_qexact   <<<64, 256, 0, stream>>>(x, wh, wl, bq, Cand, qex);
  k_mexact   <<<dim3(4, 64), 256, 0, stream>>>(qex, kf, idxs, Cand, Mex);
  k_sel45    <<<64, 64, 0, stream>>>(Mex, Cand, Mtop, MtopSlot);
  k_qreduce  <<<64, 256, 0, stream>>>(qex, MtopSlot, Qr);
  // kf dead from here; tail aliases live
  k_scores   <<<dim3(16, 64), 256, 0, stream>>>(Qr, kb16, scores);
  k_softmax  <<<dim3(45, 64), 256, 0, stream>>>(scores);
  k_outu     <<<dim3(8, 64), 256, 0, stream>>>(scores, vfT, pout);
  k_delta_fin<<<64, 256, 0, stream>>>(pout, vmean, delta);
  k_uidx_init<<<1024, 256, 0, stream>>>(uidx);
  k_scatter  <<<64, 64, 0, stream>>>(Mtop, uidx);
  k_corr     <<<dim3(45, 64), 256, 0, stream>>>(delta, Wp, Mtop, corr);
  k_base     <<<64, 256, 0, stream>>>(vmean, Wpsum, bp, basep);
  k_assemble <<<dim3(4096, 8), 256, 0, stream>>>(basep, corr, uidx, out);
}

// Round 10
// 566.916 us; speedup vs baseline: 1.1831x; 1.0075x over previous
//
#include <hip/hip_runtime.h>
#include <float.h>

typedef unsigned short ushort_t;
typedef short bf16x8 __attribute__((ext_vector_type(8)));     // 8 bf16 (guide-verified operand type)
typedef _Float16 f16x8 __attribute__((ext_vector_type(8)));   // 8 f16
typedef float f32x4 __attribute__((ext_vector_type(4)));

#define NS 4096
#define ND 64
#define NU 45
#define NUP 48

__device__ __forceinline__ float bf2f(ushort_t u){ return __uint_as_float(((unsigned)u)<<16); }
__device__ __forceinline__ ushort_t f2bf(float f){
  unsigned u = __float_as_uint(f);
  u += 0x7fffu + ((u>>16)&1u);   // RNE
  return (ushort_t)(u>>16);
}
__device__ __forceinline__ ushort_t f2h(float f){ _Float16 h=(_Float16)f; return __builtin_bit_cast(ushort_t, h); }
__device__ __forceinline__ float h2f(ushort_t u){ return (float)__builtin_bit_cast(_Float16, u); }

// ---------------------------------------------------------------------------
// 1) W split+transpose: Wq|Wk|Wv f32 [k][n] -> wh,wl bf16 [1536 n][512 k]
// ---------------------------------------------------------------------------
__global__ __launch_bounds__(256) void k_wsplit(const float* __restrict__ Wq,
                                                const float* __restrict__ Wk,
                                                const float* __restrict__ Wv,
                                                ushort_t* __restrict__ wh,
                                                ushort_t* __restrict__ wl)
{
  int i = blockIdx.x*256 + threadIdx.x;     // < 1536*512
  int c = i >> 9, k = i & 511;
  const float* W = (c < 512) ? Wq : (c < 1024 ? Wk : Wv);
  float v = W[k*512 + (c & 511)];
  ushort_t h = f2bf(v);
  wh[i] = h;
  wl[i] = f2bf(v - bf2f(h));
}

// ---------------------------------------------------------------------------
// 1b) x hi/lo split (once): x f32 -> xh,xl bf16, 4 elems/thread
// ---------------------------------------------------------------------------
__global__ __launch_bounds__(256) void k_xsplit(const float* __restrict__ x,
                                                ushort_t* __restrict__ xh,
                                                ushort_t* __restrict__ xl)
{
  int i = (blockIdx.x*256 + threadIdx.x)*4;
  float4 v = *(const float4*)(x + i);
  ushort4 h, lo;
  h.x = f2bf(v.x); lo.x = f2bf(v.x - bf2f(h.x));
  h.y = f2bf(v.y); lo.y = f2bf(v.y - bf2f(h.y));
  h.z = f2bf(v.z); lo.z = f2bf(v.z - bf2f(h.z));
  h.w = f2bf(v.w); lo.w = f2bf(v.w - bf2f(h.w));
  *(ushort4*)(xh + i) = h;
  *(ushort4*)(xl + i) = lo;
}

// ---------------------------------------------------------------------------
// 2) QKV projection (A and B staged in LDS, from precomputed splits)
//    MODE 0: q, 1-term bf16 (4 col-tiles), A from xh -> qb16 bf16 via LDS
//    MODE 1: kv, 3-term (8 col-tiles), A from xh/xl
//            -> kf f32 (+kb16 bf16 via LDS); v f16 TRANSPOSED via LDS
// ---------------------------------------------------------------------------
template<int MODE>
__global__ __launch_bounds__(256) void k_gemm(
    const ushort_t* __restrict__ xh, const ushort_t* __restrict__ xl,
    const ushort_t* __restrict__ wh, const ushort_t* __restrict__ wl,
    const float* __restrict__ bq, const float* __restrict__ bk, const float* __restrict__ bv,
    float* __restrict__ kf, ushort_t* __restrict__ vfT,
    ushort_t* __restrict__ kb16, ushort_t* __restrict__ qb16)
{
  __shared__ __align__(16) ushort_t smem[20480];      // 40 KiB stage / 34.8 KiB epilogue transpose
  ushort_t* Ah = smem;
  ushort_t* Al = smem + 5120;                          // MODE1 only
  ushort_t* Bh = smem + (MODE == 1 ? 10240 : 5120);
  ushort_t* Bl = smem + 15360;                         // MODE1 only
  const int nbx = (MODE == 0) ? 4 : 8;
  const int p = blockIdx.y * nbx + blockIdx.x;
  const int cx = p & 7;               // XCD slot
  const int local = p >> 3;
  const int by = cx*32 + local/nbx;   // 32 row-panels per XCD chunk
  const int bx = local % nbx;
  const int rowbase = by * 128;
  const int colbase = (MODE == 0 ? 0 : 512) + bx*128;
  const int mat = colbase >> 9;       // 0=q 1=k 2=v
  const int t = threadIdx.x;
  const int l = t & 63;
  const int w = t >> 6;
  const int wm = w >> 1, wn = w & 1;
  f32x4 acc[4][4] = {};
  const int r0 = t >> 2;              // 0..63
  const int c0 = (t & 3) * 8;         // elem offset within 32-wide K slab

  for (int k0 = 0; k0 < 512; k0 += 32) {
    __syncthreads();
    #pragma unroll
    for (int half = 0; half < 2; half++) {
      const int r = r0 + half*64;
      *(uint4*)(&Ah[r*40 + c0]) = *(const uint4*)(&xh[(size_t)(rowbase + r)*512 + k0 + c0]);
      if (MODE == 1) *(uint4*)(&Al[r*40 + c0]) = *(const uint4*)(&xl[(size_t)(rowbase + r)*512 + k0 + c0]);
      *(uint4*)(&Bh[r*40 + c0]) = *(const uint4*)(&wh[(size_t)(colbase + r)*512 + k0 + c0]);
      if (MODE == 1) *(uint4*)(&Bl[r*40 + c0]) = *(const uint4*)(&wl[(size_t)(colbase + r)*512 + k0 + c0]);
    }
    __syncthreads();
    bf16x8 ah[4], al[4], bh8[4], bl8[4];
    #pragma unroll
    for (int m = 0; m < 4; m++) {
      const int off = (wm*64 + m*16 + (l & 15))*40 + (l >> 4)*8;
      ah[m] = *(const bf16x8*)(&Ah[off]);
      if (MODE == 1) al[m] = *(const bf16x8*)(&Al[off]);
    }
    #pragma unroll
    for (int n = 0; n < 4; n++) {
      const int off = (wn*64 + n*16 + (l & 15))*40 + (l >> 4)*8;
      bh8[n] = *(const bf16x8*)(&Bh[off]);
      if (MODE == 1) bl8[n] = *(const bf16x8*)(&Bl[off]);
    }
    #pragma unroll
    for (int m = 0; m < 4; m++)
      #pragma unroll
      for (int n = 0; n < 4; n++) {
        acc[m][n] = __builtin_amdgcn_mfma_f32_16x16x32_bf16(ah[m], bh8[n], acc[m][n], 0, 0, 0);
        if (MODE == 1) {
          acc[m][n] = __builtin_amdgcn_mfma_f32_16x16x32_bf16(ah[m], bl8[n], acc[m][n], 0, 0, 0);
          acc[m][n] = __builtin_amdgcn_mfma_f32_16x16x32_bf16(al[m], bh8[n], acc[m][n], 0, 0, 0);
        }
      }
  }

  if (MODE == 1 && mat == 2) {
    // v: LDS transpose then coalesced 128B vfT row-segment writes
    __syncthreads();
    #pragma unroll
    for (int n = 0; n < 4; n++) {
      const int wi_l = wn*64 + n*16 + (l & 15);
      const float bias = bv[(colbase & 511) + wi_l];
      #pragma unroll
      for (int m = 0; m < 4; m++) {
        const int nr_l = wm*64 + m*16 + ((l >> 4) << 2);
        ushort4 pk;
        pk.x = f2h(acc[m][n][0] + bias);
        pk.y = f2h(acc[m][n][1] + bias);
        pk.z = f2h(acc[m][n][2] + bias);
        pk.w = f2h(acc[m][n][3] + bias);
        *(ushort4*)(&smem[wi_l*136 + nr_l]) = pk;   // [128 wi][136] f16, padded
      }
    }
    __syncthreads();
    const int wi2 = t >> 1, half = t & 1;
    const int cim = (colbase & 511) + wi2;
    const int hh2 = cim >> 6, d2 = cim & 63;
    const int b2 = rowbase >> 12;
    const int nr2 = (rowbase & 4095) + half*64;
    ushort_t* op = &vfT[((size_t)(b2*8 + hh2)*ND + d2)*NS + nr2];
    const ushort_t* ip = &smem[wi2*136 + half*64];
    #pragma unroll
    for (int cch = 0; cch < 8; cch++)
      *(uint4*)(op + cch*8) = *(const uint4*)(ip + cch*8);
    return;
  }

  if (MODE == 1) {
    // k: direct f32 writes (aligned 64B row segments)
    #pragma unroll
    for (int n = 0; n < 4; n++) {
      const int wi = (colbase & 511) + wn*64 + n*16 + (l & 15);
      const int hh = wi >> 6, d = wi & 63;
      const float bias = bk[wi];
      #pragma unroll
      for (int m = 0; m < 4; m++) {
        const int rb = rowbase + wm*64 + m*16 + ((l >> 4) << 2);
        const int b  = rb >> 12, nr = rb & 4095;
        #pragma unroll
        for (int j = 0; j < 4; j++)
          kf[((size_t)(b*8 + hh)*NS + nr + j)*ND + d] = acc[m][n][j] + bias;
      }
    }
  }
  // bf16 [bh][n][64] output via LDS: kb16 (MODE1 k) or qb16 (MODE0)
  {
    ushort_t* obuf = (MODE == 0) ? qb16 : kb16;
    const float* bias_p = (MODE == 0) ? bq : bk;
    __syncthreads();
    #pragma unroll
    for (int n = 0; n < 4; n++) {
      const int c_l = wn*64 + n*16 + (l & 15);
      const float bias = bias_p[(colbase & 511) + c_l];
      #pragma unroll
      for (int m = 0; m < 4; m++) {
        const int rb_l = wm*64 + m*16 + ((l >> 4) << 2);
        #pragma unroll
        for (int j = 0; j < 4; j++)
          smem[(rb_l + j)*136 + c_l] = f2bf(acc[m][n][j] + bias);
      }
    }
    __syncthreads();
    const int r2 = t >> 1, half = t & 1;
    const int hh2 = ((colbase & 511) >> 6) + half;
    const int b2 = rowbase >> 12;
    const int nr2 = rowbase & 4095;
    ushort_t* op = &obuf[((size_t)(b2*8 + hh2)*NS + nr2 + r2)*ND];
    const ushort_t* ip = &smem[r2*136 + half*64];
    #pragma unroll
    for (int cch = 0; cch < 8; cch++)
      *(uint4*)(op + cch*8) = *(const uint4*)(ip + cch*8);
  }
}

// ---------------------------------------------------------------------------
// 3) APPROX M from bf16 q,k: wave per query, 8 lanes per sample-row
// ---------------------------------------------------------------------------
__global__ __launch_bounds__(256) void k_m_approx(const ushort_t* __restrict__ qb16,
                                                  const ushort_t* __restrict__ kb16,
                                                  const int* __restrict__ idxs,
                                                  float* __restrict__ Mv)
{
  __shared__ float qs[4][64];
  __shared__ int   sidx[4][48];
  const int orig = blockIdx.y * 1024 + blockIdx.x;
  const int lin  = (orig & 7) * 8192 + (orig >> 3);   // bijective XCD swizzle
  const int bh   = lin >> 10;
  const int lc   = lin & 1023;
  const int t = threadIdx.x;
  const int wv = t >> 6, lane = t & 63;
  const int l = lc*4 + wv;
  qs[wv][lane] = bf2f(qb16[((size_t)bh*NS + l)*ND + lane]);
  for (int e = t; e < 4*NU; e += 256)
    sidx[e/NU][e%NU] = idxs[(size_t)(lc*4 + e/NU)*NU + e%NU];
  __syncthreads();
  const int g  = lane >> 3;       // sample group 0..7
  const int dq = lane & 7;        // 8 bf16 at dq*8
  const float* qp = &qs[wv][dq*8];
  float mx = -FLT_MAX, sm = 0.f;
  #pragma unroll
  for (int p = 0; p < 6; p++) {
    const int s = p*8 + g;
    const bool val = (s < NU);
    const int id = sidx[wv][val ? s : NU-1];
    uint4 ku = *(const uint4*)(&kb16[((size_t)bh*NS + id)*ND + dq*8]);
    const ushort_t* kp = (const ushort_t*)&ku;
    float p_dot = qp[0]*bf2f(kp[0]) + qp[1]*bf2f(kp[1]) + qp[2]*bf2f(kp[2]) + qp[3]*bf2f(kp[3])
                + qp[4]*bf2f(kp[4]) + qp[5]*bf2f(kp[5]) + qp[6]*bf2f(kp[6]) + qp[7]*bf2f(kp[7]);
    p_dot += __shfl_xor(p_dot, 1, 64);
    p_dot += __shfl_xor(p_dot, 2, 64);
    p_dot += __shfl_xor(p_dot, 4, 64);
    if (val) { mx = fmaxf(mx, p_dot); sm += p_dot; }
  }
  #pragma unroll
  for (int o = 8; o < 64; o <<= 1) {
    mx = fmaxf(mx, __shfl_xor(mx, o, 64));
    sm += __shfl_xor(sm, o, 64);
  }
  if (lane == 0) Mv[bh*NS + l] = mx - sm * (1.0f/(float)NS);
}

// ---------------------------------------------------------------------------
// 4) top-64 per (b,h): register-cached iterative argmax
// ---------------------------------------------------------------------------
template<int NSEL, int OST>
__global__ __launch_bounds__(256) void k_topk(const float* __restrict__ Mv, int* __restrict__ dst)
{
  __shared__ float wvs[4];
  __shared__ int   wis[4];
  const int bh = blockIdx.x, t = threadIdx.x;
  const int wv = t >> 6, lane = t & 63;
  float v[16];
  #pragma unroll
  for (int j = 0; j < 16; j++) v[j] = Mv[bh*NS + j*256 + t];
  unsigned removed = 0;
  float tmax = -FLT_MAX; int tidx = 0x7fffffff;
  #pragma unroll
  for (int j = 0; j < 16; j++) {
    if (v[j] > tmax) { tmax = v[j]; tidx = j*256 + t; }
  }
  for (int it = 0; it < NSEL; it++) {
    float mv = tmax; int mi = tidx;
    #pragma unroll
    for (int o = 1; o < 64; o <<= 1) {
      float vo = __shfl_xor(mv, o, 64); int io = __shfl_xor(mi, o, 64);
      if (vo > mv || (vo == mv && io < mi)) { mv = vo; mi = io; }
    }
    if (lane == 0) { wvs[wv] = mv; wis[wv] = mi; }
    __syncthreads();
    float gv = wvs[0]; int gi = wis[0];
    #pragma unroll
    for (int k2 = 1; k2 < 4; k2++) {
      float vo = wvs[k2]; int io = wis[k2];
      if (vo > gv || (vo == gv && io < gi)) { gv = vo; gi = io; }
    }
    if (t == 0) dst[bh*OST + it] = gi;
    if ((gi & 255) == t) {       // owner invalidates and rescans its 16
      removed |= 1u << (gi >> 8);
      tmax = -FLT_MAX; tidx = 0x7fffffff;
      #pragma unroll
      for (int j = 0; j < 16; j++) {
        bool ok = ((removed >> j) & 1u) == 0u;
        if (ok && (v[j] > tmax || (v[j] == tmax && (j*256+t) < tidx))) { tmax = v[j]; tidx = j*256 + t; }
      }
    }
    __syncthreads();
  }
}

// ---------------------------------------------------------------------------
// 4b) exact q for the 64 candidates: 3-term split-bf16 MFMA
//     qex[bh][cand][64] f32; one block per bh (4 waves x 16 cands x 64 cols)
// ---------------------------------------------------------------------------
__global__ __launch_bounds__(256) void k_qexact(const float* __restrict__ x,
                                                const ushort_t* __restrict__ wh,
                                                const ushort_t* __restrict__ wl,
                                                const float* __restrict__ bq,
                                                const int* __restrict__ Cand,
                                                float* __restrict__ qex)
{
  const int bh = blockIdx.x, t = threadIdx.x;
  const int wv = t >> 6, l = t & 63;
  const int b = bh >> 3, h = bh & 7;
  const int cand = 16*wv + (l & 15);
  const int n = Cand[bh*64 + cand];
  const float* xr = x + ((size_t)b*NS + n)*512 + (l >> 4)*8;
  f32x4 acc[4] = {};
  for (int k0 = 0; k0 < 512; k0 += 32) {
    float4 v0 = *(const float4*)(xr + k0);
    float4 v1 = *(const float4*)(xr + k0 + 4);
    ushort_t hi[8], lo[8];
    float vv[8] = {v0.x,v0.y,v0.z,v0.w,v1.x,v1.y,v1.z,v1.w};
    #pragma unroll
    for (int j = 0; j < 8; j++) {
      hi[j] = f2bf(vv[j]);
      lo[j] = f2bf(vv[j] - bf2f(hi[j]));
    }
    bf16x8 ah = *(const bf16x8*)hi;
    bf16x8 al = *(const bf16x8*)lo;
    #pragma unroll
    for (int nt = 0; nt < 4; nt++) {
      const size_t boff = (size_t)(h*64 + nt*16 + (l & 15))*512 + k0 + (l >> 4)*8;
      bf16x8 bh8 = *(const bf16x8*)(&wh[boff]);
      bf16x8 bl8 = *(const bf16x8*)(&wl[boff]);
      acc[nt] = __builtin_amdgcn_mfma_f32_16x16x32_bf16(ah, bh8, acc[nt], 0, 0, 0);
      acc[nt] = __builtin_amdgcn_mfma_f32_16x16x32_bf16(ah, bl8, acc[nt], 0, 0, 0);
      acc[nt] = __builtin_amdgcn_mfma_f32_16x16x32_bf16(al, bh8, acc[nt], 0, 0, 0);
    }
  }
  #pragma unroll
  for (int nt = 0; nt < 4; nt++)
    #pragma unroll
    for (int j = 0; j < 4; j++) {
      const int cand_o = 16*wv + (l >> 4)*4 + j;
      const int d_o = nt*16 + (l & 15);
      qex[((size_t)bh*64 + cand_o)*ND + d_o] = acc[nt][j] + bq[h*64 + d_o];
    }
}

// ---------------------------------------------------------------------------
// 4c) exact M for the 64 candidates: 16 lanes per candidate (reads qex, kf)
// ---------------------------------------------------------------------------
__global__ __launch_bounds__(256) void k_mexact(const float* __restrict__ qex,
                                                const float* __restrict__ kf,
                                                const int* __restrict__ idxs,
                                                const int* __restrict__ Cand,
                                                float* __restrict__ Mex)
{
  const int bh = blockIdx.y, qtr = blockIdx.x, t = threadIdx.x;
  const int c = qtr*16 + (t >> 4);
  const int dl = t & 15;                    // 4 floats at dl*4
  const int l = Cand[bh*64 + c];
  const float4 q4 = *(const float4*)(&qex[((size_t)bh*64 + c)*ND + dl*4]);
  const float* kbase = kf + (size_t)bh*NS*ND;
  const int* ib = idxs + (size_t)l*NU;
  float mx = -FLT_MAX, sm = 0.f;
  for (int s = 0; s < NU; s++) {
    const int id = ib[s];
    const float4 k4 = *(const float4*)(&kbase[(size_t)id*ND + dl*4]);
    float p = q4.x*k4.x + q4.y*k4.y + q4.z*k4.z + q4.w*k4.w;
    p += __shfl_xor(p, 1, 64);
    p += __shfl_xor(p, 2, 64);
    p += __shfl_xor(p, 4, 64);
    p += __shfl_xor(p, 8, 64);
    mx = fmaxf(mx, p);
    sm += p;
  }
  if (dl == 0) Mex[bh*64 + c] = mx - sm * (1.0f/(float)NS);
}

// 4d) exact top-45 of the 64 candidates (value desc, index asc); keeps slot
__global__ void k_sel45(const float* __restrict__ Mex, const int* __restrict__ Cand,
                        int* __restrict__ Mtop, int* __restrict__ MtopSlot)
{
  const int bh = blockIdx.x, lane = threadIdx.x;   // 64 threads
  float val = Mex[bh*64 + lane];
  const int n = Cand[bh*64 + lane];
  const int slot = lane;
  for (int it = 0; it < NU; it++) {
    float wv = val; int wn = n; int ws = slot;
    #pragma unroll
    for (int o = 1; o < 64; o <<= 1) {
      float vo = __shfl_xor(wv, o, 64); int io = __shfl_xor(wn, o, 64); int so = __shfl_xor(ws, o, 64);
      if (vo > wv || (vo == wv && io < wn)) { wv = vo; wn = io; ws = so; }
    }
    if (lane == 0) { Mtop[bh*NUP + it] = wn; MtopSlot[bh*NUP + it] = ws; }
    if (n == wn) val = -FLT_MAX;
  }
}

// ---------------------------------------------------------------------------
// 5) Q_reduce gather from qex -> bf16 [bh][48][64] (rows 45..47 zero)
// ---------------------------------------------------------------------------
__global__ __launch_bounds__(256) void k_qreduce(const float* __restrict__ qex,
                                                 const int* __restrict__ MtopSlot,
                                                 ushort_t* __restrict__ Qr)
{
  const int bh = blockIdx.x, t = threadIdx.x;
  for (int e = t; e < NUP*ND; e += 256) {
    const int u = e >> 6, d = e & 63;
    float v = 0.f;
    if (u < NU) { const int s = MtopSlot[bh*NUP + u]; v = qex[((size_t)bh*64 + s)*ND + d]; }
    Qr[bh*NUP*ND + e] = f2bf(v);
  }
}

// ---------------------------------------------------------------------------
// 6) scores[bh][48][4096] = bf16( 0.125 * Qr @ k^T ), B direct from kb16
// ---------------------------------------------------------------------------
__global__ __launch_bounds__(256) void k_scores(const ushort_t* __restrict__ Qr,
                                                const ushort_t* __restrict__ kb16,
                                                ushort_t* __restrict__ scores)
{
  __shared__ __align__(16) ushort_t Ql[NUP*80];
  const int bh = blockIdx.y;
  const int n0 = blockIdx.x * 256;
  const int t = threadIdx.x, w = t >> 6, l = t & 63;
  for (int chunk = t; chunk < NUP*8; chunk += 256) {
    const int r = chunk >> 3, cp = chunk & 7;
    *(uint4*)(&Ql[r*80 + cp*8]) = *(const uint4*)(&Qr[((size_t)bh*NUP + r)*ND + cp*8]);
  }
  __syncthreads();
  f32x4 acc[3][4] = {};
  const int nw = n0 + w*64;
  #pragma unroll
  for (int ks = 0; ks < 2; ks++) {
    bf16x8 a[3], b8[4];
    #pragma unroll
    for (int m = 0; m < 3; m++)
      a[m] = *(const bf16x8*)(&Ql[(m*16 + (l & 15))*80 + (l >> 4)*8 + ks*32]);
    #pragma unroll
    for (int n = 0; n < 4; n++)
      b8[n] = *(const bf16x8*)(&kb16[((size_t)bh*NS + nw + n*16 + (l & 15))*ND + (l >> 4)*8 + ks*32]);
    #pragma unroll
    for (int m = 0; m < 3; m++)
      #pragma unroll
      for (int n = 0; n < 4; n++)
        acc[m][n] = __builtin_amdgcn_mfma_f32_16x16x32_bf16(a[m], b8[n], acc[m][n], 0, 0, 0);
  }
  #pragma unroll
  for (int m = 0; m < 3; m++)
    #pragma unroll
    for (int n = 0; n < 4; n++)
      #pragma unroll
      for (int j = 0; j < 4; j++) {
        const int row = m*16 + (l >> 4)*4 + j;
        const int col = nw + n*16 + (l & 15);
        scores[((size_t)bh*NUP + row)*NS + col] = f2bf(acc[m][n][j] * 0.125f);
      }
}

// ---------------------------------------------------------------------------
// 7) softmax: bf16 scores row -> f16 attn row, in place (u<45 only)
// ---------------------------------------------------------------------------
__global__ __launch_bounds__(256) void k_softmax(ushort_t* __restrict__ scores)
{
  __shared__ float srow[NS];
  __shared__ float red[256];
  const int bh = blockIdx.y, u = blockIdx.x, t = threadIdx.x;
  ushort_t* row = scores + ((size_t)bh*NUP + u)*NS;
  float mx = -FLT_MAX;
  for (int j = t; j < NS; j += 256) { float v = bf2f(row[j]); srow[j] = v; mx = fmaxf(mx, v); }
  red[t] = mx; __syncthreads();
  for (int s = 128; s > 0; s >>= 1) { if (t < s) red[t] = fmaxf(red[t], red[t+s]); __syncthreads(); }
  mx = red[0]; __syncthreads();
  float sm = 0.f;
  for (int j = t; j < NS; j += 256) { const float e = __expf(srow[j] - mx); srow[j] = e; sm += e; }
  red[t] = sm; __syncthreads();
  for (int s = 128; s > 0; s >>= 1) { if (t < s) red[t] += red[t+s]; __syncthreads(); }
  const float inv = 1.0f / red[0];
  for (int j = t; j < NS; j += 256) row[j] = f2h(srow[j] * inv);
}

// ---------------------------------------------------------------------------
// 8) v mean from vfT (one block per (bh,d), deterministic)
// ---------------------------------------------------------------------------
__global__ __launch_bounds__(256) void k_vmean(const ushort_t* __restrict__ vfT, float* __restrict__ vmean)
{
  __shared__ float red[256];
  const int d = blockIdx.x, bh = blockIdx.y, t = threadIdx.x;
  const ushort_t* vr = vfT + ((size_t)bh*ND + d)*NS;
  float s = 0.f;
  for (int n = t; n < NS; n += 256) s += h2f(vr[n]);
  red[t] = s; __syncthreads();
  for (int st = 128; st > 0; st >>= 1) { if (t < st) red[t] += red[t+st]; __syncthreads(); }
  if (t == 0) vmean[bh*ND + d] = red[0] * (1.0f/(float)NS);
}

// ---------------------------------------------------------------------------
// 9) PV partials via f16 MFMA: pout[bh][ch][48][64] over 8 NS-chunks of 512
// ---------------------------------------------------------------------------
__global__ __launch_bounds__(256) void k_outu(const ushort_t* __restrict__ attn,
                                              const ushort_t* __restrict__ vfT,
                                              float* __restrict__ pout)
{
  const int bh = blockIdx.y, ch = blockIdx.x;
  const int t = threadIdx.x, w = t >> 6, l = t & 63;
  if (w >= 3) return;               // 3 row-tiles of 16 (48 rows); no syncs below
  const ushort_t* ab = attn + (size_t)bh*NUP*NS;
  const ushort_t* vb = vfT + (size_t)bh*ND*NS;
  f32x4 acc[4] = {};
  const int arow = w*16 + (l & 15);
  const int koff = (l >> 4)*8;
  const int kbeg = ch*512;
  for (int kc = kbeg; kc < kbeg + 512; kc += 32) {
    uint4 au = *(const uint4*)(&ab[(size_t)arow*NS + kc + koff]);
    f16x8 a = __builtin_bit_cast(f16x8, au);
    #pragma unroll
    for (int nt = 0; nt < 4; nt++) {
      uint4 bu = *(const uint4*)(&vb[(size_t)(nt*16 + (l & 15))*NS + kc + koff]);
      f16x8 b = __builtin_bit_cast(f16x8, bu);
      acc[nt] = __builtin_amdgcn_mfma_f32_16x16x32_f16(a, b, acc[nt], 0, 0, 0);
    }
  }
  #pragma unroll
  for (int nt = 0; nt < 4; nt++)
    #pragma unroll
    for (int j = 0; j < 4; j++) {
      const int u = w*16 + (l >> 4)*4 + j;
      const int d = nt*16 + (l & 15);
      pout[(((size_t)bh*8 + ch)*NUP + u)*ND + d] = acc[nt][j];
    }
}

__global__ __launch_bounds__(256) void k_delta_fin(const float* __restrict__ pout,
                                                   const float* __restrict__ vmean,
                                                   float* __restrict__ delta)
{
  const int bh = blockIdx.x, t = threadIdx.x;
  for (int e = t; e < NUP*ND; e += 256) {
    const int u = e >> 6, d = e & 63;
    float s = 0.f;
    #pragma unroll
    for (int ch = 0; ch < 8; ch++) s += pout[(((size_t)bh*8 + ch)*NUP + u)*ND + d];
    delta[((size_t)bh*NUP + u)*ND + d] = s - vmean[bh*ND + d];
  }
}

// ---------------------------------------------------------------------------
// 10) row-id map
// ---------------------------------------------------------------------------
__global__ __launch_bounds__(256) void k_uidx_init(int* __restrict__ uidx)
{
  uidx[blockIdx.x*256 + threadIdx.x] = -1;
}

__global__ void k_scatter(const int* __restrict__ Mtop, int* __restrict__ uidx)
{
  const int bh = blockIdx.x, t = threadIdx.x;  // 64 threads
  if (t < NU) {
    const int n = Mtop[bh*NUP + t];
    const int b = bh >> 3, h = bh & 7;
    const int nprime = h*512 + (n >> 3);       // reference's reshape-without-transpose
    uidx[((size_t)b*NS + nprime)*8 + (n & 7)] = bh*NUP + t;
  }
}

// ---------------------------------------------------------------------------
// 11) corrections: corr[bh*48+u][512] = delta @ Wp[j*64:(j+1)*64, :]   (f32)
// ---------------------------------------------------------------------------
__global__ __launch_bounds__(256) void k_corr(const float* __restrict__ delta,
                                              const float* __restrict__ Wp,
                                              const int* __restrict__ Mtop,
                                              float* __restrict__ corr)
{
  __shared__ float dl[64];
  const int bh = blockIdx.y, u = blockIdx.x, t = threadIdx.x;
  const int n = Mtop[bh*NUP + u];
  const int j = n & 7;
  if (t < 64) dl[t] = delta[((size_t)bh*NUP + u)*ND + t];
  __syncthreads();
  for (int c = t; c < 512; c += 256) {
    float s = 0.f;
    #pragma unroll 8
    for (int d2 = 0; d2 < 64; d2++) s += dl[d2] * Wp[(size_t)(j*64 + d2)*512 + c];
    corr[((size_t)bh*NUP + u)*512 + c] = s;
  }
}

// ---------------------------------------------------------------------------
// 12) Wpsum[d2][c] = sum_j Wp[j*64+d2][c]; base rows from Wpsum
// ---------------------------------------------------------------------------
__global__ __launch_bounds__(256) void k_wpsum(const float* __restrict__ Wp,
                                               float* __restrict__ Wpsum)
{
  int i = blockIdx.x*256 + threadIdx.x;   // < 64*512
  int d2 = i >> 9, c = i & 511;
  float s = 0.f;
  #pragma unroll
  for (int j = 0; j < 8; j++) s += Wp[(size_t)(j*64 + d2)*512 + c];
  Wpsum[i] = s;
}

__global__ __launch_bounds__(256) void k_base(const float* __restrict__ vmean,
                                              const float* __restrict__ Wpsum,
                                              const float* __restrict__ bp,
                                              float* __restrict__ basep)
{
  __shared__ float vm[64];
  const int bh = blockIdx.x, t = threadIdx.x;
  if (t < 64) vm[t] = vmean[bh*ND + t];
  __syncthreads();
  for (int c = t; c < 512; c += 256) {
    float s = bp[c];
    #pragma unroll 8
    for (int d2 = 0; d2 < 64; d2++) s += vm[d2] * Wpsum[d2*512 + c];
    basep[bh*512 + c] = s;
  }
}

// ---------------------------------------------------------------------------
// 13) assemble output rows (f32)
// ---------------------------------------------------------------------------
__global__ __launch_bounds__(256) void k_assemble(const float* __restrict__ basep,
                                                  const float* __restrict__ corr,
                                                  const int* __restrict__ uidx,
                                                  float* __restrict__ out)
{
  const int b = blockIdx.y, nprime = blockIdx.x, t = threadIdx.x;
  const int h = nprime >> 9;
  const int* ui = uidx + ((size_t)b*NS + nprime)*8;
  float v0 = basep[(b*8 + h)*512 + t];
  float v1 = basep[(b*8 + h)*512 + 256 + t];
  #pragma unroll
  for (int j = 0; j < 8; j++) {
    const int id = ui[j];
    if (id >= 0) { v0 += corr[(size_t)id*512 + t]; v1 += corr[(size_t)id*512 + 256 + t]; }
  }
  const size_t o = ((size_t)b*NS + nprime)*512;
  out[o + t]       = v0;
  out[o + 256 + t] = v1;
}

// ---------------------------------------------------------------------------
extern "C" void kernel_launch(void* const* d_in, const int* in_sizes, int n_in,
                              void* d_out, int out_size, void* d_ws, size_t ws_size,
                              hipStream_t stream)
{
  (void)in_sizes; (void)n_in; (void)out_size; (void)ws_size;
  const float* x  = (const float*)d_in[0];
  const float* Wq = (const float*)d_in[1];
  const float* bq = (const float*)d_in[2];
  const float* Wk = (const float*)d_in[3];
  const float* bk = (const float*)d_in[4];
  const float* Wv = (const float*)d_in[5];
  const float* bv = (const float*)d_in[6];
  const float* Wp = (const float*)d_in[7];
  const float* bp = (const float*)d_in[8];
  const int* idxs = (const int*)d_in[9];
  float* out      = (float*)d_out;

  // workspace carve-up (peak 205.7 MB; ws >= 205,975,552 established)
  char* w = (char*)d_ws;
  float*    kf    = (float*)(w);                    // 67,108,864  (dead after k_mexact -> tail aliases)
  ushort_t* vfT   = (ushort_t*)(w + 67108864);      // 33,554,432  [64][64][4096] f16
  ushort_t* kb16  = (ushort_t*)(w + 100663296);     // 33,554,432  [64][4096][64] bf16
  ushort_t* xh    = (ushort_t*)(w + 134217728);     // 33,554,432  (dead after k_gemm<0>)
  ushort_t* xl    = (ushort_t*)(w + 167772160);     // 33,554,432  (dead after k_gemm<1>)
  ushort_t* qb16  = (ushort_t*)(w + 167772160);     // ALIAS of xl: written by k_gemm<0>
  ushort_t* wh    = (ushort_t*)(w + 201326592);     //  1,572,864
  ushort_t* wl    = (ushort_t*)(w + 202899456);     //  1,572,864
  float*    Mv    = (float*)(w + 204472320);        //  1,048,576  (dead after k_topk)
  float*    qex   = (float*)(w + 204472320);        // ALIAS of Mv: [64][64][64] f32
  int*      Mtop  = (int*)(w + 205520896);          //     12,288
  int*      MtopSlot = (int*)(w + 205533184);       //     12,288
  int*      Cand  = (int*)(w + 205545472);          //     16,384
  float*    Mex   = (float*)(w + 205561856);        //     16,384
  float*    vmean = (float*)(w + 205578240);        //     16,384
  float*    Wpsum = (float*)(w + 205594624);        //    131,072  -> end 205,725,696
  // tail aliases over the dead kf region (valid after k_mexact):
  ushort_t* scores = (ushort_t*)(w);                // 25,165,824
  float*    delta  = (float*)(w + 25165824);        //    786,432
  float*    corr   = (float*)(w + 25952256);        //  6,291,456
  int*      uidx   = (int*)(w + 32243712);          //  1,048,576
  float*    basep  = (float*)(w + 33292288);        //    131,072
  float*    pout   = (float*)(w + 33423360);        //  6,291,456
  ushort_t* Qr     = (ushort_t*)(w + 39714816);     //    393,216  -> 40,108,032

  k_wsplit   <<<3072, 256, 0, stream>>>(Wq, Wk, Wv, wh, wl);
  k_xsplit   <<<16384, 256, 0, stream>>>(x, xh, xl);
  k_gemm<1>  <<<dim3(8, 256), 256, 0, stream>>>(xh, xl, wh, wl, bq, bk, bv, kf, vfT, kb16, nullptr);
  // xl dead; qb16 (same region) written next. k_gemm<0> reads only xh.
  k_gemm<0>  <<<dim3(4, 256), 256, 0, stream>>>(xh, nullptr, wh, wl, bq, bk, bv, nullptr, nullptr, nullptr, qb16);
  k_wpsum    <<<128, 256, 0, stream>>>(Wp, Wpsum);
  k_m_approx <<<dim3(1024, 64), 256, 0, stream>>>(qb16, kb16, idxs, Mv);
  k_vmean    <<<dim3(64, 64), 256, 0, stream>>>(vfT, vmean);
  k_topk<64,64> <<<64, 256, 0, stream>>>(Mv, Cand);
  // Mv dead; qex (same region) written next
  k_qexact   <<<64, 256, 0, stream>>>(x, wh, wl, bq, Cand, qex);
  k_mexact   <<<dim3(4, 64), 256, 0, stream>>>(qex, kf, idxs, Cand, Mex);
  k_sel45    <<<64, 64, 0, stream>>>(Mex, Cand, Mtop, MtopSlot);
  // kf dead from here; tail aliases live
  k_qreduce  <<<64, 256, 0, stream>>>(qex, MtopSlot, Qr);
  k_scores   <<<dim3(16, 64), 256, 0, stream>>>(Qr, kb16, scores);
  k_softmax  <<<dim3(45, 64), 256, 0, stream>>>(scores);
  k_outu     <<<dim3(8, 64), 256, 0, stream>>>(scores, vfT, pout);
  k_delta_fin<<<64, 256, 0, stream>>>(pout, vmean, delta);
  k_uidx_init<<<1024, 256, 0, stream>>>(uidx);
  k_scatter  <<<64, 64, 0, stream>>>(Mtop, uidx);
  k_corr     <<<dim3(45, 64), 256, 0, stream>>>(delta, Wp, Mtop, corr);
  k_base     <<<64, 256, 0, stream>>>(vmean, Wpsum, bp, basep);
  k_assemble <<<dim3(4096, 8), 256, 0, stream>>>(basep, corr, uidx, out);
}

// Round 11
// 547.370 us; speedup vs baseline: 1.2254x; 1.0357x over previous
//
#include <hip/hip_runtime.h>
#include <float.h>

typedef unsigned short ushort_t;
typedef short bf16x8 __attribute__((ext_vector_type(8)));     // 8 bf16 (guide-verified operand type)
typedef _Float16 f16x8 __attribute__((ext_vector_type(8)));   // 8 f16
typedef float f32x4 __attribute__((ext_vector_type(4)));

#define NS 4096
#define ND 64
#define NU 45
#define NUP 48

__device__ __forceinline__ float bf2f(ushort_t u){ return __uint_as_float(((unsigned)u)<<16); }
__device__ __forceinline__ ushort_t f2bf(float f){
  unsigned u = __float_as_uint(f);
  u += 0x7fffu + ((u>>16)&1u);   // RNE
  return (ushort_t)(u>>16);
}
__device__ __forceinline__ ushort_t f2h(float f){ _Float16 h=(_Float16)f; return __builtin_bit_cast(ushort_t, h); }
__device__ __forceinline__ float h2f(ushort_t u){ return (float)__builtin_bit_cast(_Float16, u); }

// ---------------------------------------------------------------------------
// 1) W split+transpose via LDS tiles (coalesced both sides):
//    Wq|Wk|Wv f32 [k][n] -> wh,wl bf16 [1536 n][512 k]
// ---------------------------------------------------------------------------
__global__ __launch_bounds__(256) void k_wsplit(const float* __restrict__ Wq,
                                                const float* __restrict__ Wk,
                                                const float* __restrict__ Wv,
                                                ushort_t* __restrict__ wh,
                                                ushort_t* __restrict__ wl)
{
  __shared__ float tile[64][65];
  const int blk = blockIdx.x;            // 192 = 3 mats x 8 kt x 8 nt
  const int mat = blk >> 6;
  const int kt = (blk >> 3) & 7, nt = blk & 7;
  const float* W = (mat == 0) ? Wq : (mat == 1 ? Wk : Wv);
  const int t = threadIdx.x;
  const int rr = t >> 6, cc = t & 63;
  #pragma unroll
  for (int i = 0; i < 16; i++)
    tile[rr*16 + i][cc] = W[(size_t)(kt*64 + rr*16 + i)*512 + nt*64 + cc];
  __syncthreads();
  #pragma unroll
  for (int i = 0; i < 16; i++) {
    const int n = rr*16 + i;
    const float v = tile[cc][n];         // W[kt*64+cc][nt*64+n]
    const ushort_t h = f2bf(v);
    const size_t o = (size_t)(mat*512 + nt*64 + n)*512 + kt*64 + cc;
    wh[o] = h;
    wl[o] = f2bf(v - bf2f(h));
  }
}

// ---------------------------------------------------------------------------
// 1b) x hi/lo split (once): x f32 -> xh,xl bf16, 4 elems/thread
// ---------------------------------------------------------------------------
__global__ __launch_bounds__(256) void k_xsplit(const float* __restrict__ x,
                                                ushort_t* __restrict__ xh,
                                                ushort_t* __restrict__ xl)
{
  int i = (blockIdx.x*256 + threadIdx.x)*4;
  float4 v = *(const float4*)(x + i);
  ushort4 h, lo;
  h.x = f2bf(v.x); lo.x = f2bf(v.x - bf2f(h.x));
  h.y = f2bf(v.y); lo.y = f2bf(v.y - bf2f(h.y));
  h.z = f2bf(v.z); lo.z = f2bf(v.z - bf2f(h.z));
  h.w = f2bf(v.w); lo.w = f2bf(v.w - bf2f(h.w));
  *(ushort4*)(xh + i) = h;
  *(ushort4*)(xl + i) = lo;
}

// ---------------------------------------------------------------------------
// 2) QKV projection (A and B staged in LDS, from precomputed splits)
//    MODE 0: q, 1-term bf16 (4 col-tiles), A from xh -> qb16 bf16 via LDS
//    MODE 1: kv, 3-term (8 col-tiles), A from xh/xl
//            -> kf f32 (+kb16 bf16 via LDS); v f16 TRANSPOSED via LDS
// ---------------------------------------------------------------------------
template<int MODE>
__global__ __launch_bounds__(256) void k_gemm(
    const ushort_t* __restrict__ xh, const ushort_t* __restrict__ xl,
    const ushort_t* __restrict__ wh, const ushort_t* __restrict__ wl,
    const float* __restrict__ bq, const float* __restrict__ bk, const float* __restrict__ bv,
    float* __restrict__ kf, ushort_t* __restrict__ vfT,
    ushort_t* __restrict__ kb16, ushort_t* __restrict__ qb16)
{
  __shared__ __align__(16) ushort_t smem[20480];      // 40 KiB stage / 34.8 KiB epilogue transpose
  ushort_t* Ah = smem;
  ushort_t* Al = smem + 5120;                          // MODE1 only
  ushort_t* Bh = smem + (MODE == 1 ? 10240 : 5120);
  ushort_t* Bl = smem + 15360;                         // MODE1 only
  const int nbx = (MODE == 0) ? 4 : 8;
  const int p = blockIdx.y * nbx + blockIdx.x;
  const int cx = p & 7;               // XCD slot
  const int local = p >> 3;
  const int by = cx*32 + local/nbx;   // 32 row-panels per XCD chunk
  const int bx = local % nbx;
  const int rowbase = by * 128;
  const int colbase = (MODE == 0 ? 0 : 512) + bx*128;
  const int mat = colbase >> 9;       // 0=q 1=k 2=v
  const int t = threadIdx.x;
  const int l = t & 63;
  const int w = t >> 6;
  const int wm = w >> 1, wn = w & 1;
  f32x4 acc[4][4] = {};
  const int r0 = t >> 2;              // 0..63
  const int c0 = (t & 3) * 8;         // elem offset within 32-wide K slab

  for (int k0 = 0; k0 < 512; k0 += 32) {
    __syncthreads();
    #pragma unroll
    for (int half = 0; half < 2; half++) {
      const int r = r0 + half*64;
      *(uint4*)(&Ah[r*40 + c0]) = *(const uint4*)(&xh[(size_t)(rowbase + r)*512 + k0 + c0]);
      if (MODE == 1) *(uint4*)(&Al[r*40 + c0]) = *(const uint4*)(&xl[(size_t)(rowbase + r)*512 + k0 + c0]);
      *(uint4*)(&Bh[r*40 + c0]) = *(const uint4*)(&wh[(size_t)(colbase + r)*512 + k0 + c0]);
      if (MODE == 1) *(uint4*)(&Bl[r*40 + c0]) = *(const uint4*)(&wl[(size_t)(colbase + r)*512 + k0 + c0]);
    }
    __syncthreads();
    bf16x8 ah[4], al[4], bh8[4], bl8[4];
    #pragma unroll
    for (int m = 0; m < 4; m++) {
      const int off = (wm*64 + m*16 + (l & 15))*40 + (l >> 4)*8;
      ah[m] = *(const bf16x8*)(&Ah[off]);
      if (MODE == 1) al[m] = *(const bf16x8*)(&Al[off]);
    }
    #pragma unroll
    for (int n = 0; n < 4; n++) {
      const int off = (wn*64 + n*16 + (l & 15))*40 + (l >> 4)*8;
      bh8[n] = *(const bf16x8*)(&Bh[off]);
      if (MODE == 1) bl8[n] = *(const bf16x8*)(&Bl[off]);
    }
    #pragma unroll
    for (int m = 0; m < 4; m++)
      #pragma unroll
      for (int n = 0; n < 4; n++) {
        acc[m][n] = __builtin_amdgcn_mfma_f32_16x16x32_bf16(ah[m], bh8[n], acc[m][n], 0, 0, 0);
        if (MODE == 1) {
          acc[m][n] = __builtin_amdgcn_mfma_f32_16x16x32_bf16(ah[m], bl8[n], acc[m][n], 0, 0, 0);
          acc[m][n] = __builtin_amdgcn_mfma_f32_16x16x32_bf16(al[m], bh8[n], acc[m][n], 0, 0, 0);
        }
      }
  }

  if (MODE == 1 && mat == 2) {
    // v: LDS transpose then coalesced 128B vfT row-segment writes
    __syncthreads();
    #pragma unroll
    for (int n = 0; n < 4; n++) {
      const int wi_l = wn*64 + n*16 + (l & 15);
      const float bias = bv[(colbase & 511) + wi_l];
      #pragma unroll
      for (int m = 0; m < 4; m++) {
        const int nr_l = wm*64 + m*16 + ((l >> 4) << 2);
        ushort4 pk;
        pk.x = f2h(acc[m][n][0] + bias);
        pk.y = f2h(acc[m][n][1] + bias);
        pk.z = f2h(acc[m][n][2] + bias);
        pk.w = f2h(acc[m][n][3] + bias);
        *(ushort4*)(&smem[wi_l*136 + nr_l]) = pk;   // [128 wi][136] f16, padded
      }
    }
    __syncthreads();
    const int wi2 = t >> 1, half = t & 1;
    const int cim = (colbase & 511) + wi2;
    const int hh2 = cim >> 6, d2 = cim & 63;
    const int b2 = rowbase >> 12;
    const int nr2 = (rowbase & 4095) + half*64;
    ushort_t* op = &vfT[((size_t)(b2*8 + hh2)*ND + d2)*NS + nr2];
    const ushort_t* ip = &smem[wi2*136 + half*64];
    #pragma unroll
    for (int cch = 0; cch < 8; cch++)
      *(uint4*)(op + cch*8) = *(const uint4*)(ip + cch*8);
    return;
  }

  if (MODE == 1) {
    // k: direct f32 writes (aligned 64B row segments)
    #pragma unroll
    for (int n = 0; n < 4; n++) {
      const int wi = (colbase & 511) + wn*64 + n*16 + (l & 15);
      const int hh = wi >> 6, d = wi & 63;
      const float bias = bk[wi];
      #pragma unroll
      for (int m = 0; m < 4; m++) {
        const int rb = rowbase + wm*64 + m*16 + ((l >> 4) << 2);
        const int b  = rb >> 12, nr = rb & 4095;
        #pragma unroll
        for (int j = 0; j < 4; j++)
          kf[((size_t)(b*8 + hh)*NS + nr + j)*ND + d] = acc[m][n][j] + bias;
      }
    }
  }
  // bf16 [bh][n][64] output via LDS: kb16 (MODE1 k) or qb16 (MODE0)
  {
    ushort_t* obuf = (MODE == 0) ? qb16 : kb16;
    const float* bias_p = (MODE == 0) ? bq : bk;
    __syncthreads();
    #pragma unroll
    for (int n = 0; n < 4; n++) {
      const int c_l = wn*64 + n*16 + (l & 15);
      const float bias = bias_p[(colbase & 511) + c_l];
      #pragma unroll
      for (int m = 0; m < 4; m++) {
        const int rb_l = wm*64 + m*16 + ((l >> 4) << 2);
        #pragma unroll
        for (int j = 0; j < 4; j++)
          smem[(rb_l + j)*136 + c_l] = f2bf(acc[m][n][j] + bias);
      }
    }
    __syncthreads();
    const int r2 = t >> 1, half = t & 1;
    const int hh2 = ((colbase & 511) >> 6) + half;
    const int b2 = rowbase >> 12;
    const int nr2 = rowbase & 4095;
    ushort_t* op = &obuf[((size_t)(b2*8 + hh2)*NS + nr2 + r2)*ND];
    const ushort_t* ip = &smem[r2*136 + half*64];
    #pragma unroll
    for (int cch = 0; cch < 8; cch++)
      *(uint4*)(op + cch*8) = *(const uint4*)(ip + cch*8);
  }
}

// ---------------------------------------------------------------------------
// 3) APPROX M from bf16 q,k: wave per query, 8 lanes per sample-row,
//    all 6 gathers force-hoisted into registers (deep MLP)
// ---------------------------------------------------------------------------
__global__ __launch_bounds__(256) void k_m_approx(const ushort_t* __restrict__ qb16,
                                                  const ushort_t* __restrict__ kb16,
                                                  const int* __restrict__ idxs,
                                                  float* __restrict__ Mv)
{
  __shared__ float qs[4][64];
  __shared__ int   sidx[4][48];
  const int orig = blockIdx.y * 1024 + blockIdx.x;
  const int lin  = (orig & 7) * 8192 + (orig >> 3);   // bijective XCD swizzle
  const int bh   = lin >> 10;
  const int lc   = lin & 1023;
  const int t = threadIdx.x;
  const int wv = t >> 6, lane = t & 63;
  const int l = lc*4 + wv;
  qs[wv][lane] = bf2f(qb16[((size_t)bh*NS + l)*ND + lane]);
  for (int e = t; e < 4*NU; e += 256)
    sidx[e/NU][e%NU] = idxs[(size_t)(lc*4 + e/NU)*NU + e%NU];
  __syncthreads();
  const int g  = lane >> 3;       // sample group 0..7
  const int dq = lane & 7;        // 8 bf16 at dq*8
  const float* qp = &qs[wv][dq*8];
  int ids[6];
  #pragma unroll
  for (int p = 0; p < 6; p++) {
    const int s = p*8 + g;
    ids[p] = sidx[wv][(s < NU) ? s : NU-1];
  }
  uint4 ku[6];
  #pragma unroll
  for (int p = 0; p < 6; p++)
    ku[p] = *(const uint4*)(&kb16[((size_t)bh*NS + ids[p])*ND + dq*8]);
  float mx = -FLT_MAX, sm = 0.f;
  #pragma unroll
  for (int p = 0; p < 6; p++) {
    const int s = p*8 + g;
    const bool val = (s < NU);
    const ushort_t* kp = (const ushort_t*)&ku[p];
    float p_dot = qp[0]*bf2f(kp[0]) + qp[1]*bf2f(kp[1]) + qp[2]*bf2f(kp[2]) + qp[3]*bf2f(kp[3])
                + qp[4]*bf2f(kp[4]) + qp[5]*bf2f(kp[5]) + qp[6]*bf2f(kp[6]) + qp[7]*bf2f(kp[7]);
    p_dot += __shfl_xor(p_dot, 1, 64);
    p_dot += __shfl_xor(p_dot, 2, 64);
    p_dot += __shfl_xor(p_dot, 4, 64);
    if (val) { mx = fmaxf(mx, p_dot); sm += p_dot; }
  }
  #pragma unroll
  for (int o = 8; o < 64; o <<= 1) {
    mx = fmaxf(mx, __shfl_xor(mx, o, 64));
    sm += __shfl_xor(sm, o, 64);
  }
  if (lane == 0) Mv[bh*NS + l] = mx - sm * (1.0f/(float)NS);
}

// ---------------------------------------------------------------------------
// 4) top-64 per (b,h): register-cached iterative argmax
// ---------------------------------------------------------------------------
template<int NSEL, int OST>
__global__ __launch_bounds__(256) void k_topk(const float* __restrict__ Mv, int* __restrict__ dst)
{
  __shared__ float wvs[4];
  __shared__ int   wis[4];
  const int bh = blockIdx.x, t = threadIdx.x;
  const int wv = t >> 6, lane = t & 63;
  float v[16];
  #pragma unroll
  for (int j = 0; j < 16; j++) v[j] = Mv[bh*NS + j*256 + t];
  unsigned removed = 0;
  float tmax = -FLT_MAX; int tidx = 0x7fffffff;
  #pragma unroll
  for (int j = 0; j < 16; j++) {
    if (v[j] > tmax) { tmax = v[j]; tidx = j*256 + t; }
  }
  for (int it = 0; it < NSEL; it++) {
    float mv = tmax; int mi = tidx;
    #pragma unroll
    for (int o = 1; o < 64; o <<= 1) {
      float vo = __shfl_xor(mv, o, 64); int io = __shfl_xor(mi, o, 64);
      if (vo > mv || (vo == mv && io < mi)) { mv = vo; mi = io; }
    }
    if (lane == 0) { wvs[wv] = mv; wis[wv] = mi; }
    __syncthreads();
    float gv = wvs[0]; int gi = wis[0];
    #pragma unroll
    for (int k2 = 1; k2 < 4; k2++) {
      float vo = wvs[k2]; int io = wis[k2];
      if (vo > gv || (vo == gv && io < gi)) { gv = vo; gi = io; }
    }
    if (t == 0) dst[bh*OST + it] = gi;
    if ((gi & 255) == t) {       // owner invalidates and rescans its 16
      removed |= 1u << (gi >> 8);
      tmax = -FLT_MAX; tidx = 0x7fffffff;
      #pragma unroll
      for (int j = 0; j < 16; j++) {
        bool ok = ((removed >> j) & 1u) == 0u;
        if (ok && (v[j] > tmax || (v[j] == tmax && (j*256+t) < tidx))) { tmax = v[j]; tidx = j*256 + t; }
      }
    }
    __syncthreads();
  }
}

// ---------------------------------------------------------------------------
// 4b) exact q for the 64 candidates: 3-term split-bf16 MFMA
// ---------------------------------------------------------------------------
__global__ __launch_bounds__(256) void k_qexact(const float* __restrict__ x,
                                                const ushort_t* __restrict__ wh,
                                                const ushort_t* __restrict__ wl,
                                                const float* __restrict__ bq,
                                                const int* __restrict__ Cand,
                                                float* __restrict__ qex)
{
  const int bh = blockIdx.x, t = threadIdx.x;
  const int wv = t >> 6, l = t & 63;
  const int b = bh >> 3, h = bh & 7;
  const int cand = 16*wv + (l & 15);
  const int n = Cand[bh*64 + cand];
  const float* xr = x + ((size_t)b*NS + n)*512 + (l >> 4)*8;
  f32x4 acc[4] = {};
  for (int k0 = 0; k0 < 512; k0 += 32) {
    float4 v0 = *(const float4*)(xr + k0);
    float4 v1 = *(const float4*)(xr + k0 + 4);
    ushort_t hi[8], lo[8];
    float vv[8] = {v0.x,v0.y,v0.z,v0.w,v1.x,v1.y,v1.z,v1.w};
    #pragma unroll
    for (int j = 0; j < 8; j++) {
      hi[j] = f2bf(vv[j]);
      lo[j] = f2bf(vv[j] - bf2f(hi[j]));
    }
    bf16x8 ah = *(const bf16x8*)hi;
    bf16x8 al = *(const bf16x8*)lo;
    #pragma unroll
    for (int nt = 0; nt < 4; nt++) {
      const size_t boff = (size_t)(h*64 + nt*16 + (l & 15))*512 + k0 + (l >> 4)*8;
      bf16x8 bh8 = *(const bf16x8*)(&wh[boff]);
      bf16x8 bl8 = *(const bf16x8*)(&wl[boff]);
      acc[nt] = __builtin_amdgcn_mfma_f32_16x16x32_bf16(ah, bh8, acc[nt], 0, 0, 0);
      acc[nt] = __builtin_amdgcn_mfma_f32_16x16x32_bf16(ah, bl8, acc[nt], 0, 0, 0);
      acc[nt] = __builtin_amdgcn_mfma_f32_16x16x32_bf16(al, bh8, acc[nt], 0, 0, 0);
    }
  }
  #pragma unroll
  for (int nt = 0; nt < 4; nt++)
    #pragma unroll
    for (int j = 0; j < 4; j++) {
      const int cand_o = 16*wv + (l >> 4)*4 + j;
      const int d_o = nt*16 + (l & 15);
      qex[((size_t)bh*64 + cand_o)*ND + d_o] = acc[nt][j] + bq[h*64 + d_o];
    }
}

// ---------------------------------------------------------------------------
// 4c) exact M for the 64 candidates: 16 lanes per candidate (reads qex, kf)
// ---------------------------------------------------------------------------
__global__ __launch_bounds__(256) void k_mexact(const float* __restrict__ qex,
                                                const float* __restrict__ kf,
                                                const int* __restrict__ idxs,
                                                const int* __restrict__ Cand,
                                                float* __restrict__ Mex)
{
  const int bh = blockIdx.y, qtr = blockIdx.x, t = threadIdx.x;
  const int c = qtr*16 + (t >> 4);
  const int dl = t & 15;                    // 4 floats at dl*4
  const int l = Cand[bh*64 + c];
  const float4 q4 = *(const float4*)(&qex[((size_t)bh*64 + c)*ND + dl*4]);
  const float* kbase = kf + (size_t)bh*NS*ND;
  const int* ib = idxs + (size_t)l*NU;
  float mx = -FLT_MAX, sm = 0.f;
  for (int s = 0; s < NU; s++) {
    const int id = ib[s];
    const float4 k4 = *(const float4*)(&kbase[(size_t)id*ND + dl*4]);
    float p = q4.x*k4.x + q4.y*k4.y + q4.z*k4.z + q4.w*k4.w;
    p += __shfl_xor(p, 1, 64);
    p += __shfl_xor(p, 2, 64);
    p += __shfl_xor(p, 4, 64);
    p += __shfl_xor(p, 8, 64);
    mx = fmaxf(mx, p);
    sm += p;
  }
  if (dl == 0) Mex[bh*64 + c] = mx - sm * (1.0f/(float)NS);
}

// 4d) exact top-45 of the 64 candidates (value desc, index asc); keeps slot
__global__ void k_sel45(const float* __restrict__ Mex, const int* __restrict__ Cand,
                        int* __restrict__ Mtop, int* __restrict__ MtopSlot)
{
  const int bh = blockIdx.x, lane = threadIdx.x;   // 64 threads
  float val = Mex[bh*64 + lane];
  const int n = Cand[bh*64 + lane];
  const int slot = lane;
  for (int it = 0; it < NU; it++) {
    float wv = val; int wn = n; int ws = slot;
    #pragma unroll
    for (int o = 1; o < 64; o <<= 1) {
      float vo = __shfl_xor(wv, o, 64); int io = __shfl_xor(wn, o, 64); int so = __shfl_xor(ws, o, 64);
      if (vo > wv || (vo == wv && io < wn)) { wv = vo; wn = io; ws = so; }
    }
    if (lane == 0) { Mtop[bh*NUP + it] = wn; MtopSlot[bh*NUP + it] = ws; }
    if (n == wn) val = -FLT_MAX;
  }
}

// ---------------------------------------------------------------------------
// 5) Q_reduce gather from qex -> bf16 [bh][48][64], PRE-SCALED by 0.125
//    (exact in bf16: power-of-2 scale; rows 45..47 zero)
// ---------------------------------------------------------------------------
__global__ __launch_bounds__(256) void k_qreduce(const float* __restrict__ qex,
                                                 const int* __restrict__ MtopSlot,
                                                 ushort_t* __restrict__ Qr)
{
  const int bh = blockIdx.x, t = threadIdx.x;
  for (int e = t; e < NUP*ND; e += 256) {
    const int u = e >> 6, d = e & 63;
    float v = 0.f;
    if (u < NU) { const int s = MtopSlot[bh*NUP + u]; v = qex[((size_t)bh*64 + s)*ND + d]; }
    Qr[bh*NUP*ND + e] = f2bf(v * 0.125f);
  }
}

// ---------------------------------------------------------------------------
// 6) FLASH: fused scores->softmax->PV with online softmax.
//    Grid 512 = 64 bh x 8 col-segments (blk&63=bh keeps bh on one XCD).
//    Waves 0-2 each own 16 q-rows; per 64-col chunk: QK^T (bf16 MFMA),
//    online max/rescale, P->f16 via wave-private LDS, PV (f16 MFMA, B=vfT).
//    Outputs per-segment partials (O, m, l).
// ---------------------------------------------------------------------------
__global__ __launch_bounds__(256) void k_flash(const ushort_t* __restrict__ Qr,
                                               const ushort_t* __restrict__ kb16,
                                               const ushort_t* __restrict__ vfT,
                                               float* __restrict__ Opart,
                                               float* __restrict__ mpart,
                                               float* __restrict__ lpart)
{
  __shared__ __align__(16) ushort_t Plds[3][16][68];   // f16, stride 68 (writes conflict-free, reads 2-way)
  const int blk = blockIdx.x;
  const int bh = blk & 63, seg = blk >> 6;
  const int t = threadIdx.x, w = t >> 6, l = t & 63;
  if (w >= 3) return;                                  // no barriers below (wave-private LDS)
  const int row0 = w*16;
  bf16x8 aq[2];
  #pragma unroll
  for (int ks = 0; ks < 2; ks++)
    aq[ks] = *(const bf16x8*)(&Qr[((size_t)bh*NUP + row0 + (l & 15))*ND + ks*32 + (l >> 4)*8]);
  f32x4 o[4] = {};
  float m[4], ls[4];
  #pragma unroll
  for (int j = 0; j < 4; j++) { m[j] = -FLT_MAX; ls[j] = 0.f; }
  const int nbeg = seg*512;
  for (int nc = nbeg; nc < nbeg + 512; nc += 64) {
    // QK^T: 4 col-tiles of 16 (S already x0.125 via pre-scaled Qr)
    f32x4 S[4];
    #pragma unroll
    for (int ct = 0; ct < 4; ct++) {
      f32x4 z = {};
      #pragma unroll
      for (int ks = 0; ks < 2; ks++) {
        bf16x8 bk8 = *(const bf16x8*)(&kb16[((size_t)bh*NS + nc + ct*16 + (l & 15))*ND + ks*32 + (l >> 4)*8]);
        z = __builtin_amdgcn_mfma_f32_16x16x32_bf16(aq[ks], bk8, z, 0, 0, 0);
      }
      S[ct] = z;
    }
    // running row-max (rows live in 16-lane groups)
    float mx[4];
    #pragma unroll
    for (int j = 0; j < 4; j++)
      mx[j] = fmaxf(fmaxf(S[0][j], S[1][j]), fmaxf(S[2][j], S[3][j]));
    #pragma unroll
    for (int o2 = 1; o2 < 16; o2 <<= 1)
      #pragma unroll
      for (int j = 0; j < 4; j++)
        mx[j] = fmaxf(mx[j], __shfl_xor(mx[j], o2, 64));
    float c[4];
    #pragma unroll
    for (int j = 0; j < 4; j++) {
      const float mn = fmaxf(m[j], mx[j]);
      c[j] = __expf(m[j] - mn);
      m[j] = mn;
      ls[j] *= c[j];
    }
    #pragma unroll
    for (int dt = 0; dt < 4; dt++)
      #pragma unroll
      for (int j = 0; j < 4; j++)
        o[dt][j] *= c[j];
    // P = exp(S - m), lsum accumulate (per-lane partial), stage f16
    #pragma unroll
    for (int ct = 0; ct < 4; ct++)
      #pragma unroll
      for (int j = 0; j < 4; j++) {
        const float pv = __expf(S[ct][j] - m[j]);
        ls[j] += pv;
        Plds[w][(l >> 4)*4 + j][ct*16 + (l & 15)] = f2h(pv);
      }
    // PV: A = P (LDS), B = vfT rows (d-major layout = B-operand direct)
    #pragma unroll
    for (int ks2 = 0; ks2 < 2; ks2++) {
      f16x8 ap = __builtin_bit_cast(f16x8, *(const uint4*)(&Plds[w][l & 15][ks2*32 + (l >> 4)*8]));
      #pragma unroll
      for (int dt = 0; dt < 4; dt++) {
        f16x8 bv8 = __builtin_bit_cast(f16x8, *(const uint4*)(&vfT[((size_t)bh*ND + dt*16 + (l & 15))*NS + nc + ks2*32 + (l >> 4)*8]));
        o[dt] = __builtin_amdgcn_mfma_f32_16x16x32_f16(ap, bv8, o[dt], 0, 0, 0);
      }
    }
  }
  // finalize per-row lsum across the 16-lane group
  #pragma unroll
  for (int o2 = 1; o2 < 16; o2 <<= 1)
    #pragma unroll
    for (int j = 0; j < 4; j++)
      ls[j] += __shfl_xor(ls[j], o2, 64);
  #pragma unroll
  for (int dt = 0; dt < 4; dt++)
    #pragma unroll
    for (int j = 0; j < 4; j++)
      Opart[(((size_t)bh*8 + seg)*NUP + row0 + (l >> 4)*4 + j)*ND + dt*16 + (l & 15)] = o[dt][j];
  if ((l & 15) == 0) {
    #pragma unroll
    for (int j = 0; j < 4; j++) {
      mpart[((size_t)bh*8 + seg)*NUP + row0 + (l >> 4)*4 + j] = m[j];
      lpart[((size_t)bh*8 + seg)*NUP + row0 + (l >> 4)*4 + j] = ls[j];
    }
  }
}

// ---------------------------------------------------------------------------
// 6b) combine 8 segment partials -> delta = out_u - vmean
// ---------------------------------------------------------------------------
__global__ __launch_bounds__(256) void k_combine(const float* __restrict__ Opart,
                                                 const float* __restrict__ mpart,
                                                 const float* __restrict__ lpart,
                                                 const float* __restrict__ vmean,
                                                 float* __restrict__ delta)
{
  const int bh = blockIdx.x, t = threadIdx.x;
  for (int e = t; e < NUP*ND; e += 256) {
    const int u = e >> 6, d = e & 63;
    float mg = -FLT_MAX;
    #pragma unroll
    for (int s = 0; s < 8; s++) mg = fmaxf(mg, mpart[((size_t)bh*8 + s)*NUP + u]);
    float On = 0.f, Ln = 0.f;
    #pragma unroll
    for (int s = 0; s < 8; s++) {
      const float wgt = __expf(mpart[((size_t)bh*8 + s)*NUP + u] - mg);
      On += wgt * Opart[(((size_t)bh*8 + s)*NUP + u)*ND + d];
      Ln += wgt * lpart[((size_t)bh*8 + s)*NUP + u];
    }
    delta[((size_t)bh*NUP + u)*ND + d] = On/Ln - vmean[bh*ND + d];
  }
}

// ---------------------------------------------------------------------------
// 8) v mean from vfT (one block per (bh,d), deterministic)
// ---------------------------------------------------------------------------
__global__ __launch_bounds__(256) void k_vmean(const ushort_t* __restrict__ vfT, float* __restrict__ vmean)
{
  __shared__ float red[256];
  const int d = blockIdx.x, bh = blockIdx.y, t = threadIdx.x;
  const ushort_t* vr = vfT + ((size_t)bh*ND + d)*NS;
  float s = 0.f;
  for (int n = t; n < NS; n += 256) s += h2f(vr[n]);
  red[t] = s; __syncthreads();
  for (int st = 128; st > 0; st >>= 1) { if (t < st) red[t] += red[t+st]; __syncthreads(); }
  if (t == 0) vmean[bh*ND + d] = red[0] * (1.0f/(float)NS);
}

// ---------------------------------------------------------------------------
// 10) row-id map
// ---------------------------------------------------------------------------
__global__ __launch_bounds__(256) void k_uidx_init(int* __restrict__ uidx)
{
  uidx[blockIdx.x*256 + threadIdx.x] = -1;
}

__global__ void k_scatter(const int* __restrict__ Mtop, int* __restrict__ uidx)
{
  const int bh = blockIdx.x, t = threadIdx.x;  // 64 threads
  if (t < NU) {
    const int n = Mtop[bh*NUP + t];
    const int b = bh >> 3, h = bh & 7;
    const int nprime = h*512 + (n >> 3);       // reference's reshape-without-transpose
    uidx[((size_t)b*NS + nprime)*8 + (n & 7)] = bh*NUP + t;
  }
}

// ---------------------------------------------------------------------------
// 11) corrections: corr[bh*48+u][512] = delta @ Wp[j*64:(j+1)*64, :]   (f32)
// ---------------------------------------------------------------------------
__global__ __launch_bounds__(256) void k_corr(const float* __restrict__ delta,
                                              const float* __restrict__ Wp,
                                              const int* __restrict__ Mtop,
                                              float* __restrict__ corr)
{
  __shared__ float dl[64];
  const int bh = blockIdx.y, u = blockIdx.x, t = threadIdx.x;
  const int n = Mtop[bh*NUP + u];
  const int j = n & 7;
  if (t < 64) dl[t] = delta[((size_t)bh*NUP + u)*ND + t];
  __syncthreads();
  for (int c = t; c < 512; c += 256) {
    float s = 0.f;
    #pragma unroll 8
    for (int d2 = 0; d2 < 64; d2++) s += dl[d2] * Wp[(size_t)(j*64 + d2)*512 + c];
    corr[((size_t)bh*NUP + u)*512 + c] = s;
  }
}

// ---------------------------------------------------------------------------
// 12) Wpsum[d2][c] = sum_j Wp[j*64+d2][c]; base rows from Wpsum
// ---------------------------------------------------------------------------
__global__ __launch_bounds__(256) void k_wpsum(const float* __restrict__ Wp,
                                               float* __restrict__ Wpsum)
{
  int i = blockIdx.x*256 + threadIdx.x;   // < 64*512
  int d2 = i >> 9, c = i & 511;
  float s = 0.f;
  #pragma unroll
  for (int j = 0; j < 8; j++) s += Wp[(size_t)(j*64 + d2)*512 + c];
  Wpsum[i] = s;
}

__global__ __launch_bounds__(256) void k_base(const float* __restrict__ vmean,
                                              const float* __restrict__ Wpsum,
                                              const float* __restrict__ bp,
                                              float* __restrict__ basep)
{
  __shared__ float vm[64];
  const int bh = blockIdx.x, t = threadIdx.x;
  if (t < 64) vm[t] = vmean[bh*ND + t];
  __syncthreads();
  for (int c = t; c < 512; c += 256) {
    float s = bp[c];
    #pragma unroll 8
    for (int d2 = 0; d2 < 64; d2++) s += vm[d2] * Wpsum[d2*512 + c];
    basep[bh*512 + c] = s;
  }
}

// ---------------------------------------------------------------------------
// 13) assemble output rows (f32)
// ---------------------------------------------------------------------------
__global__ __launch_bounds__(256) void k_assemble(const float* __restrict__ basep,
                                                  const float* __restrict__ corr,
                                                  const int* __restrict__ uidx,
                                                  float* __restrict__ out)
{
  const int b = blockIdx.y, nprime = blockIdx.x, t = threadIdx.x;
  const int h = nprime >> 9;
  const int* ui = uidx + ((size_t)b*NS + nprime)*8;
  float v0 = basep[(b*8 + h)*512 + t];
  float v1 = basep[(b*8 + h)*512 + 256 + t];
  #pragma unroll
  for (int j = 0; j < 8; j++) {
    const int id = ui[j];
    if (id >= 0) { v0 += corr[(size_t)id*512 + t]; v1 += corr[(size_t)id*512 + 256 + t]; }
  }
  const size_t o = ((size_t)b*NS + nprime)*512;
  out[o + t]       = v0;
  out[o + 256 + t] = v1;
}

// ---------------------------------------------------------------------------
extern "C" void kernel_launch(void* const* d_in, const int* in_sizes, int n_in,
                              void* d_out, int out_size, void* d_ws, size_t ws_size,
                              hipStream_t stream)
{
  (void)in_sizes; (void)n_in; (void)out_size; (void)ws_size;
  const float* x  = (const float*)d_in[0];
  const float* Wq = (const float*)d_in[1];
  const float* bq = (const float*)d_in[2];
  const float* Wk = (const float*)d_in[3];
  const float* bk = (const float*)d_in[4];
  const float* Wv = (const float*)d_in[5];
  const float* bv = (const float*)d_in[6];
  const float* Wp = (const float*)d_in[7];
  const float* bp = (const float*)d_in[8];
  const int* idxs = (const int*)d_in[9];
  float* out      = (float*)d_out;

  // workspace carve-up (peak 205.7 MB; ws >= 205,975,552 established)
  char* w = (char*)d_ws;
  float*    kf    = (float*)(w);                    // 67,108,864  (dead after k_mexact -> tail aliases)
  ushort_t* vfT   = (ushort_t*)(w + 67108864);      // 33,554,432  [64][64][4096] f16
  ushort_t* kb16  = (ushort_t*)(w + 100663296);     // 33,554,432  [64][4096][64] bf16
  ushort_t* xh    = (ushort_t*)(w + 134217728);     // 33,554,432  (dead after k_gemm<0>)
  ushort_t* xl    = (ushort_t*)(w + 167772160);     // 33,554,432  (dead after k_gemm<1>)
  ushort_t* qb16  = (ushort_t*)(w + 167772160);     // ALIAS of xl: written by k_gemm<0>
  ushort_t* wh    = (ushort_t*)(w + 201326592);     //  1,572,864
  ushort_t* wl    = (ushort_t*)(w + 202899456);     //  1,572,864
  float*    Mv    = (float*)(w + 204472320);        //  1,048,576  (dead after k_topk)
  float*    qex   = (float*)(w + 204472320);        // ALIAS of Mv: [64][64][64] f32
  int*      Mtop  = (int*)(w + 205520896);          //     12,288
  int*      MtopSlot = (int*)(w + 205533184);       //     12,288
  int*      Cand  = (int*)(w + 205545472);          //     16,384
  float*    Mex   = (float*)(w + 205561856);        //     16,384
  float*    vmean = (float*)(w + 205578240);        //     16,384
  float*    Wpsum = (float*)(w + 205594624);        //    131,072  -> end 205,725,696
  // tail aliases over the dead kf region (valid after k_mexact):
  float*    delta  = (float*)(w);                   //    786,432
  float*    corr   = (float*)(w + 786432);          //  6,291,456
  int*      uidx   = (int*)(w + 7077888);           //  1,048,576
  float*    basep  = (float*)(w + 8126464);         //    131,072
  float*    Opart  = (float*)(w + 8257536);         //  6,291,456  [64][8][48][64]
  float*    mpart  = (float*)(w + 14548992);        //     98,304  [64][8][48]
  float*    lpart  = (float*)(w + 14647296);        //     98,304
  ushort_t* Qr     = (ushort_t*)(w + 14745600);     //    393,216  -> 15,138,816

  k_wsplit   <<<192, 256, 0, stream>>>(Wq, Wk, Wv, wh, wl);
  k_xsplit   <<<16384, 256, 0, stream>>>(x, xh, xl);
  k_gemm<1>  <<<dim3(8, 256), 256, 0, stream>>>(xh, xl, wh, wl, bq, bk, bv, kf, vfT, kb16, nullptr);
  // xl dead; qb16 (same region) written next. k_gemm<0> reads only xh.
  k_gemm<0>  <<<dim3(4, 256), 256, 0, stream>>>(xh, nullptr, wh, wl, bq, bk, bv, nullptr, nullptr, nullptr, qb16);
  k_wpsum    <<<128, 256, 0, stream>>>(Wp, Wpsum);
  k_m_approx <<<dim3(1024, 64), 256, 0, stream>>>(qb16, kb16, idxs, Mv);
  k_vmean    <<<dim3(64, 64), 256, 0, stream>>>(vfT, vmean);
  k_topk<64,64> <<<64, 256, 0, stream>>>(Mv, Cand);
  // Mv dead; qex (same region) written next
  k_qexact   <<<64, 256, 0, stream>>>(x, wh, wl, bq, Cand, qex);
  k_mexact   <<<dim3(4, 64), 256, 0, stream>>>(qex, kf, idxs, Cand, Mex);
  k_sel45    <<<64, 64, 0, stream>>>(Mex, Cand, Mtop, MtopSlot);
  // kf dead from here; tail aliases live
  k_qreduce  <<<64, 256, 0, stream>>>(qex, MtopSlot, Qr);
  k_flash    <<<512, 256, 0, stream>>>(Qr, kb16, vfT, Opart, mpart, lpart);
  k_combine  <<<64, 256, 0, stream>>>(Opart, mpart, lpart, vmean, delta);
  k_uidx_init<<<1024, 256, 0, stream>>>(uidx);
  k_scatter  <<<64, 64, 0, stream>>>(Mtop, uidx);
  k_corr     <<<dim3(45, 64), 256, 0, stream>>>(delta, Wp, Mtop, corr);
  k_base     <<<64, 256, 0, stream>>>(vmean, Wpsum, bp, basep);
  k_assemble <<<dim3(4096, 8), 256, 0, stream>>>(basep, corr, uidx, out);
}